// Round 2
// baseline (354.677 us; speedup 1.0000x reference)
//
#include <hip/hip_runtime.h>
#include <hip/hip_fp16.h>

#define NN 50000
#define NE 800000
#define C_IN 384
#define C_HID 128
#define NB 196    // ceil(NN/256)
#define CHK 128   // edge chunks
#define ECH 6250  // edges per chunk (128*6250 = 800000)
#define NBKT 128  // dst buckets
#define BSTR 392  // dst stride per bucket (128*392 = 50176 >= NN)

typedef __attribute__((ext_vector_type(8))) short short8;
typedef __attribute__((ext_vector_type(4))) float f32x4;
typedef __attribute__((ext_vector_type(4))) unsigned short us4;

__device__ __forceinline__ ushort f2bf(float x) {
    uint u = __float_as_uint(x);
    uint r = (u + 0x7fffu + ((u >> 16) & 1u)) >> 16;  // RNE
    return (ushort)r;
}
__device__ __forceinline__ float bf2f(ushort b) { return __uint_as_float(((uint)b) << 16); }

__global__ __launch_bounds__(256) void k_dinv(const int* __restrict__ cnt,
                                              float* __restrict__ dinv) {
    int i = blockIdx.x * 256 + threadIdx.x;
    if (i < NN) dinv[i] = rsqrtf((float)cnt[i] + 1.0f);  // +1 = self loop
}

// ---------------- hierarchical exclusive scan over NN counts -> rowptr ----------------
__global__ __launch_bounds__(256) void k_bsum(const int* __restrict__ cnt,
                                              int* __restrict__ bsum) {
    __shared__ int part[256];
    const int tid = threadIdx.x;
    const int i = blockIdx.x * 256 + tid;
    part[tid] = (i < NN) ? cnt[i] : 0;
    __syncthreads();
#pragma unroll
    for (int off = 128; off > 0; off >>= 1) {
        if (tid < off) part[tid] += part[tid + off];
        __syncthreads();
    }
    if (tid == 0) bsum[blockIdx.x] = part[0];
}

__global__ __launch_bounds__(256) void k_sbs(const int* __restrict__ bsum,
                                             int* __restrict__ bpre) {
    __shared__ int part[256];
    const int t = threadIdx.x;
    part[t] = (t < NB) ? bsum[t] : 0;
    __syncthreads();
#pragma unroll
    for (int off = 1; off < 256; off <<= 1) {
        int v = (t >= off) ? part[t - off] : 0;
        __syncthreads();
        part[t] += v;
        __syncthreads();
    }
    if (t < NB) bpre[t] = (t == 0) ? 0 : part[t - 1];  // exclusive
}

__global__ __launch_bounds__(256) void k_write(const int* __restrict__ cnt,
                                               const int* __restrict__ bpre,
                                               int* __restrict__ rowptr) {
    __shared__ int part[256];
    const int t = threadIdx.x;
    const int i = blockIdx.x * 256 + t;
    const int v = (i < NN) ? cnt[i] : 0;
    part[t] = v;
    __syncthreads();
#pragma unroll
    for (int off = 1; off < 256; off <<= 1) {
        int u = (t >= off) ? part[t - off] : 0;
        __syncthreads();
        part[t] += u;
        __syncthreads();
    }
    if (i < NN) {
        const int excl = bpre[blockIdx.x] + part[t] - v;
        rowptr[i] = excl;
        if (i == NN - 1) rowptr[NN] = excl + v;
    }
}

// ---------------- bucket pipeline: hist -> hscan -> binscat -> bcnt -> binfill ----------------
__global__ __launch_bounds__(256) void k_hist(const int* __restrict__ dst,
                                              int* __restrict__ histT) {
    __shared__ int h[NBKT];
    const int tid = threadIdx.x;
    if (tid < NBKT) h[tid] = 0;
    __syncthreads();
    const int base = blockIdx.x * ECH;
    for (int i = base + tid; i < base + ECH; i += 256)
        atomicAdd(&h[(uint)dst[i] / BSTR], 1);
    __syncthreads();
    if (tid < NBKT) histT[tid * CHK + blockIdx.x] = h[tid];
}

__global__ __launch_bounds__(1024) void k_hscan(const int* __restrict__ histT,
                                                int* __restrict__ histS) {
    __shared__ int part[1024];
    const int t = threadIdx.x;
    const int base = t * 16;
    int loc[16];
    int s = 0;
#pragma unroll
    for (int i = 0; i < 16; ++i) {
        loc[i] = histT[base + i];
        s += loc[i];
    }
    part[t] = s;
    __syncthreads();
    for (int off = 1; off < 1024; off <<= 1) {
        int v = (t >= off) ? part[t - off] : 0;
        __syncthreads();
        part[t] += v;
        __syncthreads();
    }
    int run = (t == 0) ? 0 : part[t - 1];
#pragma unroll
    for (int i = 0; i < 16; ++i) {
        histS[base + i] = run;
        run += loc[i];
    }
}

// k_binscat: chunks re-read edges, write (dst, src<<16) to bucket-major mid[]
__global__ __launch_bounds__(256) void k_binscat(const int* __restrict__ src,
                                                 const int* __restrict__ dst,
                                                 const int* __restrict__ histS,
                                                 uint2* __restrict__ mid) {
    __shared__ int cur[NBKT];
    const int tid = threadIdx.x;
    if (tid < NBKT) cur[tid] = histS[tid * CHK + blockIdx.x];
    __syncthreads();
    const int base = blockIdx.x * ECH;
    for (int i = base + tid; i < base + ECH; i += 256) {
        const int s = src[i];
        const int d = dst[i];
        const int p = atomicAdd(&cur[(uint)d / BSTR], 1);
        mid[p] = make_uint2((uint)d, (uint)s << 16);
    }
}

// k_bcnt: per-node degree counts from bucketed mid (replaces global atomic k_deg)
__global__ __launch_bounds__(256) void k_bcnt(const uint2* __restrict__ mid,
                                              const int* __restrict__ histS,
                                              int* __restrict__ cnt) {
    __shared__ int cur[BSTR];
    const int tid = threadIdx.x;
    const int b = blockIdx.x;
    for (int j = tid; j < BSTR; j += 256) cur[j] = 0;
    __syncthreads();
    const int lo = histS[b * CHK];
    const int hi = (b < NBKT - 1) ? histS[(b + 1) * CHK] : NE;
    for (int e = lo + tid; e < hi; e += 256)
        atomicAdd(&cur[mid[e].x - (uint)b * BSTR], 1);
    __syncthreads();
    for (int j = tid; j < BSTR; j += 256) {
        const int idx = b * BSTR + j;
        if (idx < NN) cnt[idx] = cur[j];
    }
}

// k_binfill: one block per bucket; computes norm, scatter confined to ~25 KB csr window
__global__ __launch_bounds__(256) void k_binfill(const uint2* __restrict__ mid,
                                                 const int* __restrict__ histS,
                                                 const int* __restrict__ rowptr,
                                                 const float* __restrict__ dinv,
                                                 uint* __restrict__ csr) {
    __shared__ int cur[BSTR];
    __shared__ float sdv[BSTR];
    const int tid = threadIdx.x;
    const int b = blockIdx.x;
    for (int j = tid; j < BSTR; j += 256) {
        const int idx = b * BSTR + j;
        cur[j] = (idx < NN) ? rowptr[idx] : 0;
        sdv[j] = (idx < NN) ? dinv[idx] : 0.f;
    }
    __syncthreads();
    const int lo = histS[b * CHK];
    const int hi = (b < NBKT - 1) ? histS[(b + 1) * CHK] : NE;
    for (int e = lo + tid; e < hi; e += 256) {
        const uint2 u = mid[e];
        const int j = u.x - (uint)b * BSTR;
        const float norm = dinv[u.y >> 16] * sdv[j];
        const int p = atomicAdd(&cur[j], 1);
        csr[p] = u.y | __half_as_ushort(__float2half(norm));
    }
}

// ---------------- W -> fragment-linear hi/lo bf16 split (once per launch) ----------------
__global__ __launch_bounds__(256) void k_wconv(const float* __restrict__ W,
                                               ushort* __restrict__ Wt,
                                               int K) {
    int i = blockIdx.x * 256 + threadIdx.x;
    if (i < K * C_HID) {
        int k = i >> 7, n = i & 127;  // N = 128
        float w = W[i];
        ushort h = f2bf(w);
        ushort l = f2bf(w - bf2f(h));
        int blk = k >> 6, khalf = (k >> 5) & 1, kq = (k >> 3) & 3, j = k & 7;
        int t = n >> 4, fr = n & 15, lane = kq * 16 + fr;
        size_t off = (size_t)blk * 16384 + (size_t)((khalf * 8 + t) * 64 + lane) * 8 + j;
        Wt[off] = h;
        Wt[off + 8192] = l;
    }
}

// ---------------- split-bf16 MFMA GEMM, BM=32, barrier-free (W direct from L2) ----------------
// 4 waves: g = wv>>1 -> rows [bm+g*16, +16); ch = wv&1 -> col tiles [ch*4, ch*4+4)
// W tile is identical across all blocks -> L2/L3-resident; LDS staging removed.
template <bool IN_RELU_BIAS, bool OUT_BIAS>
__global__ __launch_bounds__(256, 4) void k_gemm_mfma(const float* __restrict__ X,
                                                      const ushort* __restrict__ Wt,
                                                      const float* __restrict__ bin,
                                                      const float* __restrict__ bout,
                                                      const float* __restrict__ dinv,
                                                      ushort* __restrict__ out_main,
                                                      float* __restrict__ out_self,
                                                      int K) {
    const int tid = threadIdx.x;
    const int bm = blockIdx.x * 32;
    const int wv = tid >> 6;
    const int lane = tid & 63;
    const int fr = lane & 15;
    const int kq = lane >> 4;
    const int g = wv >> 1;
    const int ch = wv & 1;

    int row = bm + g * 16 + fr;
    if (row >= NN) row = NN - 1;  // clamp (stores guarded)
    const float* xrow = X + (size_t)row * K + kq * 8;
    const short8* Wt8 = (const short8*)Wt;

    f32x4 acc[4];
#pragma unroll
    for (int t = 0; t < 4; ++t) acc[t] = (f32x4){0.f, 0.f, 0.f, 0.f};

    // prologue: load iter-0 A
    float4 xa0 = *(const float4*)(xrow);
    float4 xa1 = *(const float4*)(xrow + 4);
    float4 xb0 = *(const float4*)(xrow + 32);
    float4 xb1 = *(const float4*)(xrow + 36);

    for (int k0 = 0; k0 < K; k0 += 64) {
        // ---- issue this k-block's B loads first (L2-hot, coalesced 16B/lane) ----
        const short8* gB = Wt8 + (size_t)(k0 >> 6) * 2048;
        short8 b_h0[4], b_l0[4], b_h1[4], b_l1[4];
#pragma unroll
        for (int t = 0; t < 4; ++t) {
            const int tt = ch * 4 + t;
            b_h0[t] = gB[tt * 64 + lane];
            b_l0[t] = gB[1024 + tt * 64 + lane];
            b_h1[t] = gB[(8 + tt) * 64 + lane];
            b_l1[t] = gB[1024 + (8 + tt) * 64 + lane];
        }

        // ---- convert current A to hi/lo bf16 frags (VALU, overlaps B loads) ----
        float xv[16] = {xa0.x, xa0.y, xa0.z, xa0.w, xa1.x, xa1.y, xa1.z, xa1.w,
                        xb0.x, xb0.y, xb0.z, xb0.w, xb1.x, xb1.y, xb1.z, xb1.w};
        if (IN_RELU_BIAS) {
            const float* bp = bin + k0 + kq * 8;
            float4 b0 = *(const float4*)(bp);
            float4 b1 = *(const float4*)(bp + 4);
            float4 b2 = *(const float4*)(bp + 32);
            float4 b3 = *(const float4*)(bp + 36);
            const float bb[16] = {b0.x, b0.y, b0.z, b0.w, b1.x, b1.y, b1.z, b1.w,
                                  b2.x, b2.y, b2.z, b2.w, b3.x, b3.y, b3.z, b3.w};
#pragma unroll
            for (int j = 0; j < 16; ++j) xv[j] = fmaxf(xv[j] + bb[j], 0.f);
        }
        union { ushort u[8]; short8 v; } ah0, al0, ah1, al1;
#pragma unroll
        for (int j = 0; j < 8; ++j) {
            uint u = __float_as_uint(xv[j]);
            ah0.u[j] = (ushort)(u >> 16);
            al0.u[j] = (ushort)(__float_as_uint(xv[j] - __uint_as_float(u & 0xffff0000u)) >> 16);
            uint w = __float_as_uint(xv[8 + j]);
            ah1.u[j] = (ushort)(w >> 16);
            al1.u[j] = (ushort)(__float_as_uint(xv[8 + j] - __uint_as_float(w & 0xffff0000u)) >> 16);
        }

        // ---- prefetch next iter's A while B loads land / MFMA runs ----
        if (k0 + 64 < K) {
            const float* ap = xrow + k0 + 64;
            xa0 = *(const float4*)(ap);
            xa1 = *(const float4*)(ap + 4);
            xb0 = *(const float4*)(ap + 32);
            xb1 = *(const float4*)(ap + 36);
        }

        // ---- MFMA over this wave's 4 column tiles ----
#pragma unroll
        for (int t = 0; t < 4; ++t) {
            acc[t] = __builtin_amdgcn_mfma_f32_16x16x32_bf16(ah0.v, b_h0[t], acc[t], 0, 0, 0);
            acc[t] = __builtin_amdgcn_mfma_f32_16x16x32_bf16(ah0.v, b_l0[t], acc[t], 0, 0, 0);
            acc[t] = __builtin_amdgcn_mfma_f32_16x16x32_bf16(al0.v, b_h0[t], acc[t], 0, 0, 0);
            acc[t] = __builtin_amdgcn_mfma_f32_16x16x32_bf16(ah1.v, b_h1[t], acc[t], 0, 0, 0);
            acc[t] = __builtin_amdgcn_mfma_f32_16x16x32_bf16(ah1.v, b_l1[t], acc[t], 0, 0, 0);
            acc[t] = __builtin_amdgcn_mfma_f32_16x16x32_bf16(al1.v, b_h1[t], acc[t], 0, 0, 0);
        }
    }

    // ---- epilogue: D(lane,reg): m = bm + g*16 + kq*4 + r, n = (ch*4+t)*16 + fr ----
#pragma unroll
    for (int r = 0; r < 4; ++r) {
        const int m = bm + g * 16 + kq * 4 + r;
        if (m < NN) {
            const float dv = dinv[m];
            const float d2 = dv * dv;
            ushort* om = out_main + (size_t)m * C_HID;
            float* os = out_self + (size_t)m * C_HID;
#pragma unroll
            for (int t = 0; t < 4; ++t) {
                const int n = (ch * 4 + t) * 16 + fr;
                const float v = acc[t][r];
                om[n] = f2bf(v);
                os[n] = v * d2 + (OUT_BIAS ? bout[n] : 0.f);
            }
        }
    }
}

// ---------------- CSR gather: out[d] = init(out[d]) + sum_e bf16(h[src_e])*norm_e ----------------
__global__ __launch_bounds__(256) void k_gather(const ushort* __restrict__ h,
                                                const int* __restrict__ rowptr,
                                                const uint* __restrict__ csr,
                                                float* __restrict__ out) {
    const int tid = threadIdx.x;
    const int node = blockIdx.x * 8 + (tid >> 5);
    if (node >= NN) return;
    const int lane = tid & 31;
    const int c = lane * 4;
    const int beg = rowptr[node];
    const int end = rowptr[node + 1];

    float4 acc = *(const float4*)(out + (size_t)node * C_HID + c);  // self-loop init

    for (int j0 = beg; j0 < end; j0 += 32) {
        const int n = end - j0;
        uint myE = 0;
        if (lane < n) myE = csr[j0 + lane];
        const int m = n < 32 ? n : 32;
        int jj = 0;
        for (; jj + 4 <= m; jj += 4) {
            const uint e0 = (uint)__shfl((int)myE, jj + 0, 32);
            const uint e1 = (uint)__shfl((int)myE, jj + 1, 32);
            const uint e2 = (uint)__shfl((int)myE, jj + 2, 32);
            const uint e3 = (uint)__shfl((int)myE, jj + 3, 32);
            const us4 u0 = *(const us4*)(h + (size_t)(e0 >> 16) * C_HID + c);
            const us4 u1 = *(const us4*)(h + (size_t)(e1 >> 16) * C_HID + c);
            const us4 u2 = *(const us4*)(h + (size_t)(e2 >> 16) * C_HID + c);
            const us4 u3 = *(const us4*)(h + (size_t)(e3 >> 16) * C_HID + c);
            const float n0 = __half2float(__ushort_as_half((ushort)(e0 & 0xffffu)));
            const float n1 = __half2float(__ushort_as_half((ushort)(e1 & 0xffffu)));
            const float n2 = __half2float(__ushort_as_half((ushort)(e2 & 0xffffu)));
            const float n3 = __half2float(__ushort_as_half((ushort)(e3 & 0xffffu)));
            acc.x = fmaf(bf2f(u0[0]), n0, acc.x);
            acc.y = fmaf(bf2f(u0[1]), n0, acc.y);
            acc.z = fmaf(bf2f(u0[2]), n0, acc.z);
            acc.w = fmaf(bf2f(u0[3]), n0, acc.w);
            acc.x = fmaf(bf2f(u1[0]), n1, acc.x);
            acc.y = fmaf(bf2f(u1[1]), n1, acc.y);
            acc.z = fmaf(bf2f(u1[2]), n1, acc.z);
            acc.w = fmaf(bf2f(u1[3]), n1, acc.w);
            acc.x = fmaf(bf2f(u2[0]), n2, acc.x);
            acc.y = fmaf(bf2f(u2[1]), n2, acc.y);
            acc.z = fmaf(bf2f(u2[2]), n2, acc.z);
            acc.w = fmaf(bf2f(u2[3]), n2, acc.w);
            acc.x = fmaf(bf2f(u3[0]), n3, acc.x);
            acc.y = fmaf(bf2f(u3[1]), n3, acc.y);
            acc.z = fmaf(bf2f(u3[2]), n3, acc.z);
            acc.w = fmaf(bf2f(u3[3]), n3, acc.w);
        }
        for (; jj < m; ++jj) {
            const uint ev = (uint)__shfl((int)myE, jj, 32);
            const us4 u = *(const us4*)(h + (size_t)(ev >> 16) * C_HID + c);
            const float nw = __half2float(__ushort_as_half((ushort)(ev & 0xffffu)));
            acc.x = fmaf(bf2f(u[0]), nw, acc.x);
            acc.y = fmaf(bf2f(u[1]), nw, acc.y);
            acc.z = fmaf(bf2f(u[2]), nw, acc.z);
            acc.w = fmaf(bf2f(u[3]), nw, acc.w);
        }
    }
    *(float4*)(out + (size_t)node * C_HID + c) = acc;
}

extern "C" void kernel_launch(void* const* d_in, const int* in_sizes, int n_in,
                              void* d_out, int out_size, void* d_ws, size_t ws_size,
                              hipStream_t stream) {
    const float* x = (const float*)d_in[0];
    const int* ei = (const int*)d_in[1];
    const float* W1 = (const float*)d_in[2];
    const float* b1 = (const float*)d_in[3];
    const float* W2 = (const float*)d_in[4];
    const float* b2 = (const float*)d_in[5];
    float* out = (float*)d_out;

    const int* src = ei;
    const int* dst = ei + NE;

    // workspace layout (4-byte units)
    int* cnt = (int*)d_ws;                       // 50048
    int* rowptr = cnt + 50048;                   // 50064 (NN+1)
    float* dinv = (float*)(rowptr + 50064);      // 50048
    int* bsum = (int*)(dinv + 50048);            // 256
    int* bpre = bsum + 256;                      // 256
    int* histT = bpre + 256;                     // 16384
    int* histS = histT + 16384;                  // 16384
    ushort* Wt1 = (ushort*)(histS + 16384);      // 98304 shorts (frag-linear hi+lo)
    ushort* Wt2 = Wt1 + 98304;                   // 32768 shorts
    uint* csr = (uint*)(Wt2 + 32768);            // NE uints
    uint2* mid = (uint2*)(csr + NE);             // NE uint2
    ushort* A_bf = (ushort*)(mid + NE);          // NN*128 shorts (h bf16)
    float* B = (float*)(A_bf + (size_t)NN * C_HID);  // NN*128 fp32 (agg buffer)

    k_wconv<<<(C_IN * C_HID + 255) / 256, 256, 0, stream>>>(W1, Wt1, C_IN);
    k_wconv<<<(C_HID * C_HID + 255) / 256, 256, 0, stream>>>(W2, Wt2, C_HID);
    k_hist<<<CHK, 256, 0, stream>>>(dst, histT);
    k_hscan<<<1, 1024, 0, stream>>>(histT, histS);
    k_binscat<<<CHK, 256, 0, stream>>>(src, dst, histS, mid);
    k_bcnt<<<NBKT, 256, 0, stream>>>(mid, histS, cnt);
    k_dinv<<<NB, 256, 0, stream>>>(cnt, dinv);
    k_bsum<<<NB, 256, 0, stream>>>(cnt, bsum);
    k_sbs<<<1, 256, 0, stream>>>(bsum, bpre);
    k_write<<<NB, 256, 0, stream>>>(cnt, bpre, rowptr);
    k_binfill<<<NBKT, 256, 0, stream>>>(mid, histS, rowptr, dinv, csr);

    const int gblocks = (NN + 31) / 32;
    const int agblocks = (NN + 7) / 8;
    // layer 1: h1 = x@W1 -> A_bf (bf16) ;  B = h1*dinv^2 (fp32 self-loop init)
    k_gemm_mfma<false, false><<<gblocks, 256, 0, stream>>>(x, Wt1, nullptr, nullptr, dinv, A_bf, B, C_IN);
    // B += gather(h1)
    k_gather<<<agblocks, 256, 0, stream>>>(A_bf, rowptr, csr, B);
    // layer 2: h2 = relu(B + b1)@W2 -> A_bf ; out = h2*dinv^2 + b2 (self-loop init)
    k_gemm_mfma<true, true><<<gblocks, 256, 0, stream>>>(B, Wt2, b1, b2, dinv, A_bf, out, C_HID);
    // out += gather(h2)
    k_gather<<<agblocks, 256, 0, stream>>>(A_bf, rowptr, csr, out);
}

// Round 4
// 326.195 us; speedup vs baseline: 1.0873x; 1.0873x over previous
//
#include <hip/hip_runtime.h>
#include <hip/hip_fp16.h>

#define NN 50000
#define NE 800000
#define C_IN 384
#define C_HID 128
#define NB 196    // ceil(NN/256)
#define CHK 128   // edge chunks
#define ECH 6250  // edges per chunk (128*6250 = 800000)
#define NBKT 128  // dst buckets
#define BSTR 392  // dst stride per bucket (128*392 = 50176 >= NN)

typedef __attribute__((ext_vector_type(8))) short short8;
typedef __attribute__((ext_vector_type(4))) float f32x4;
typedef __attribute__((ext_vector_type(4))) unsigned short us4;

__device__ __forceinline__ ushort f2bf(float x) {
    uint u = __float_as_uint(x);
    uint r = (u + 0x7fffu + ((u >> 16) & 1u)) >> 16;  // RNE
    return (ushort)r;
}
__device__ __forceinline__ float bf2f(ushort b) { return __uint_as_float(((uint)b) << 16); }

__global__ __launch_bounds__(256) void k_dinv(const int* __restrict__ cnt,
                                              float* __restrict__ dinv) {
    int i = blockIdx.x * 256 + threadIdx.x;
    if (i < NN) dinv[i] = rsqrtf((float)cnt[i] + 1.0f);  // +1 = self loop
}

// ---------------- hierarchical exclusive scan over NN counts -> rowptr ----------------
__global__ __launch_bounds__(256) void k_bsum(const int* __restrict__ cnt,
                                              int* __restrict__ bsum) {
    __shared__ int part[256];
    const int tid = threadIdx.x;
    const int i = blockIdx.x * 256 + tid;
    part[tid] = (i < NN) ? cnt[i] : 0;
    __syncthreads();
#pragma unroll
    for (int off = 128; off > 0; off >>= 1) {
        if (tid < off) part[tid] += part[tid + off];
        __syncthreads();
    }
    if (tid == 0) bsum[blockIdx.x] = part[0];
}

__global__ __launch_bounds__(256) void k_sbs(const int* __restrict__ bsum,
                                             int* __restrict__ bpre) {
    __shared__ int part[256];
    const int t = threadIdx.x;
    part[t] = (t < NB) ? bsum[t] : 0;
    __syncthreads();
#pragma unroll
    for (int off = 1; off < 256; off <<= 1) {
        int v = (t >= off) ? part[t - off] : 0;
        __syncthreads();
        part[t] += v;
        __syncthreads();
    }
    if (t < NB) bpre[t] = (t == 0) ? 0 : part[t - 1];  // exclusive
}

__global__ __launch_bounds__(256) void k_write(const int* __restrict__ cnt,
                                               const int* __restrict__ bpre,
                                               int* __restrict__ rowptr) {
    __shared__ int part[256];
    const int t = threadIdx.x;
    const int i = blockIdx.x * 256 + t;
    const int v = (i < NN) ? cnt[i] : 0;
    part[t] = v;
    __syncthreads();
#pragma unroll
    for (int off = 1; off < 256; off <<= 1) {
        int u = (t >= off) ? part[t - off] : 0;
        __syncthreads();
        part[t] += u;
        __syncthreads();
    }
    if (i < NN) {
        const int excl = bpre[blockIdx.x] + part[t] - v;
        rowptr[i] = excl;
        if (i == NN - 1) rowptr[NN] = excl + v;
    }
}

// ---------------- bucket pipeline: hist -> hscan -> binscat -> bcnt -> binfill ----------------
__global__ __launch_bounds__(256) void k_hist(const int* __restrict__ dst,
                                              int* __restrict__ histT) {
    __shared__ int h[NBKT];
    const int tid = threadIdx.x;
    if (tid < NBKT) h[tid] = 0;
    __syncthreads();
    const int base = blockIdx.x * ECH;
    for (int i = base + tid; i < base + ECH; i += 256)
        atomicAdd(&h[(uint)dst[i] / BSTR], 1);
    __syncthreads();
    if (tid < NBKT) histT[tid * CHK + blockIdx.x] = h[tid];
}

__global__ __launch_bounds__(1024) void k_hscan(const int* __restrict__ histT,
                                                int* __restrict__ histS) {
    __shared__ int part[1024];
    const int t = threadIdx.x;
    const int base = t * 16;
    int loc[16];
    int s = 0;
#pragma unroll
    for (int i = 0; i < 16; ++i) {
        loc[i] = histT[base + i];
        s += loc[i];
    }
    part[t] = s;
    __syncthreads();
    for (int off = 1; off < 1024; off <<= 1) {
        int v = (t >= off) ? part[t - off] : 0;
        __syncthreads();
        part[t] += v;
        __syncthreads();
    }
    int run = (t == 0) ? 0 : part[t - 1];
#pragma unroll
    for (int i = 0; i < 16; ++i) {
        histS[base + i] = run;
        run += loc[i];
    }
}

// k_binscat: chunks re-read edges, write (dst, src<<16) to bucket-major mid[]
__global__ __launch_bounds__(256) void k_binscat(const int* __restrict__ src,
                                                 const int* __restrict__ dst,
                                                 const int* __restrict__ histS,
                                                 uint2* __restrict__ mid) {
    __shared__ int cur[NBKT];
    const int tid = threadIdx.x;
    if (tid < NBKT) cur[tid] = histS[tid * CHK + blockIdx.x];
    __syncthreads();
    const int base = blockIdx.x * ECH;
    for (int i = base + tid; i < base + ECH; i += 256) {
        const int s = src[i];
        const int d = dst[i];
        const int p = atomicAdd(&cur[(uint)d / BSTR], 1);
        mid[p] = make_uint2((uint)d, (uint)s << 16);
    }
}

// k_bcnt: per-node degree counts from bucketed mid (replaces global atomic k_deg)
__global__ __launch_bounds__(256) void k_bcnt(const uint2* __restrict__ mid,
                                              const int* __restrict__ histS,
                                              int* __restrict__ cnt) {
    __shared__ int cur[BSTR];
    const int tid = threadIdx.x;
    const int b = blockIdx.x;
    for (int j = tid; j < BSTR; j += 256) cur[j] = 0;
    __syncthreads();
    const int lo = histS[b * CHK];
    const int hi = (b < NBKT - 1) ? histS[(b + 1) * CHK] : NE;
    for (int e = lo + tid; e < hi; e += 256)
        atomicAdd(&cur[mid[e].x - (uint)b * BSTR], 1);
    __syncthreads();
    for (int j = tid; j < BSTR; j += 256) {
        const int idx = b * BSTR + j;
        if (idx < NN) cnt[idx] = cur[j];
    }
}

// k_binfill: one block per bucket; computes norm, scatter confined to ~25 KB csr window
__global__ __launch_bounds__(256) void k_binfill(const uint2* __restrict__ mid,
                                                 const int* __restrict__ histS,
                                                 const int* __restrict__ rowptr,
                                                 const float* __restrict__ dinv,
                                                 uint* __restrict__ csr) {
    __shared__ int cur[BSTR];
    __shared__ float sdv[BSTR];
    const int tid = threadIdx.x;
    const int b = blockIdx.x;
    for (int j = tid; j < BSTR; j += 256) {
        const int idx = b * BSTR + j;
        cur[j] = (idx < NN) ? rowptr[idx] : 0;
        sdv[j] = (idx < NN) ? dinv[idx] : 0.f;
    }
    __syncthreads();
    const int lo = histS[b * CHK];
    const int hi = (b < NBKT - 1) ? histS[(b + 1) * CHK] : NE;
    for (int e = lo + tid; e < hi; e += 256) {
        const uint2 u = mid[e];
        const int j = u.x - (uint)b * BSTR;
        const float norm = dinv[u.y >> 16] * sdv[j];
        const int p = atomicAdd(&cur[j], 1);
        csr[p] = u.y | __half_as_ushort(__float2half(norm));
    }
}

// ---------------- W -> fragment-linear hi/lo bf16 split (once per launch) ----------------
__global__ __launch_bounds__(256) void k_wconv(const float* __restrict__ W,
                                               ushort* __restrict__ Wt,
                                               int K) {
    int i = blockIdx.x * 256 + threadIdx.x;
    if (i < K * C_HID) {
        int k = i >> 7, n = i & 127;  // N = 128
        float w = W[i];
        ushort h = f2bf(w);
        ushort l = f2bf(w - bf2f(h));
        int blk = k >> 6, khalf = (k >> 5) & 1, kq = (k >> 3) & 3, j = k & 7;
        int t = n >> 4, fr = n & 15, lane = kq * 16 + fr;
        size_t off = (size_t)blk * 16384 + (size_t)((khalf * 8 + t) * 64 + lane) * 8 + j;
        Wt[off] = h;
        Wt[off + 8192] = l;
    }
}

// ---------------- split-bf16 MFMA GEMM, BM=32, barrier-free, tile-pipelined B ----------------
// 4 waves: g = wv>>1 -> rows [bm+g*16, +16); ch = wv&1 -> col tiles [ch*4, ch*4+4)
// W tile identical across blocks -> L2/L3-resident; B double-buffered in regs (named, static).
#define LOADB0(KBLK, TT)                                   \
    {                                                      \
        const short8* gB_ = Wt8 + (size_t)(KBLK) * 2048;   \
        b00 = gB_[(TT) * 64 + lane];                       \
        b01 = gB_[1024 + (TT) * 64 + lane];                \
        b02 = gB_[(8 + (TT)) * 64 + lane];                 \
        b03 = gB_[1024 + (8 + (TT)) * 64 + lane];          \
    }
#define LOADB1(KBLK, TT)                                   \
    {                                                      \
        const short8* gB_ = Wt8 + (size_t)(KBLK) * 2048;   \
        b10 = gB_[(TT) * 64 + lane];                       \
        b11 = gB_[1024 + (TT) * 64 + lane];                \
        b12 = gB_[(8 + (TT)) * 64 + lane];                 \
        b13 = gB_[1024 + (8 + (TT)) * 64 + lane];          \
    }
#define MFMA6(BH0, BL0, BH1, BL1, T)                                                     \
    acc[T] = __builtin_amdgcn_mfma_f32_16x16x32_bf16(ah0.v, BH0, acc[T], 0, 0, 0);       \
    acc[T] = __builtin_amdgcn_mfma_f32_16x16x32_bf16(ah0.v, BL0, acc[T], 0, 0, 0);       \
    acc[T] = __builtin_amdgcn_mfma_f32_16x16x32_bf16(al0.v, BH0, acc[T], 0, 0, 0);       \
    acc[T] = __builtin_amdgcn_mfma_f32_16x16x32_bf16(ah1.v, BH1, acc[T], 0, 0, 0);       \
    acc[T] = __builtin_amdgcn_mfma_f32_16x16x32_bf16(ah1.v, BL1, acc[T], 0, 0, 0);       \
    acc[T] = __builtin_amdgcn_mfma_f32_16x16x32_bf16(al1.v, BH1, acc[T], 0, 0, 0);

template <bool IN_RELU_BIAS, bool OUT_BIAS>
__global__ __launch_bounds__(256) void k_gemm_mfma(const float* __restrict__ X,
                                                   const ushort* __restrict__ Wt,
                                                   const float* __restrict__ bin,
                                                   const float* __restrict__ bout,
                                                   const float* __restrict__ dinv,
                                                   ushort* __restrict__ out_main,
                                                   float* __restrict__ out_self,
                                                   int K) {
    const int tid = threadIdx.x;
    const int bm = blockIdx.x * 32;
    const int wv = tid >> 6;
    const int lane = tid & 63;
    const int fr = lane & 15;
    const int kq = lane >> 4;
    const int g = wv >> 1;
    const int ch = wv & 1;
    const int tb = ch * 4;  // first col tile of this wave

    int row = bm + g * 16 + fr;
    if (row >= NN) row = NN - 1;  // clamp (stores guarded)
    const float* xrow = X + (size_t)row * K + kq * 8;
    const short8* Wt8 = (const short8*)Wt;

    f32x4 acc[4];
#pragma unroll
    for (int t = 0; t < 4; ++t) acc[t] = (f32x4){0.f, 0.f, 0.f, 0.f};

    // prologue: iter-0 A loads + tile-0 B loads (buffer 0)
    float4 xa0 = *(const float4*)(xrow);
    float4 xa1 = *(const float4*)(xrow + 4);
    float4 xb0 = *(const float4*)(xrow + 32);
    float4 xb1 = *(const float4*)(xrow + 36);
    short8 b00, b01, b02, b03, b10, b11, b12, b13;
    LOADB0(0, tb);

    for (int k0 = 0; k0 < K; k0 += 64) {
        const int kb = k0 >> 6;

        // ---- convert current A to hi/lo bf16 frags (VALU; overlaps in-flight B loads) ----
        float xv[16] = {xa0.x, xa0.y, xa0.z, xa0.w, xa1.x, xa1.y, xa1.z, xa1.w,
                        xb0.x, xb0.y, xb0.z, xb0.w, xb1.x, xb1.y, xb1.z, xb1.w};
        if (IN_RELU_BIAS) {
            const float* bp = bin + k0 + kq * 8;
            float4 c0 = *(const float4*)(bp);
            float4 c1 = *(const float4*)(bp + 4);
            float4 c2 = *(const float4*)(bp + 32);
            float4 c3 = *(const float4*)(bp + 36);
            const float bb[16] = {c0.x, c0.y, c0.z, c0.w, c1.x, c1.y, c1.z, c1.w,
                                  c2.x, c2.y, c2.z, c2.w, c3.x, c3.y, c3.z, c3.w};
#pragma unroll
            for (int j = 0; j < 16; ++j) xv[j] = fmaxf(xv[j] + bb[j], 0.f);
        }
        union { ushort u[8]; short8 v; } ah0, al0, ah1, al1;
#pragma unroll
        for (int j = 0; j < 8; ++j) {
            uint u = __float_as_uint(xv[j]);
            ah0.u[j] = (ushort)(u >> 16);
            al0.u[j] = (ushort)(__float_as_uint(xv[j] - __uint_as_float(u & 0xffff0000u)) >> 16);
            uint w = __float_as_uint(xv[8 + j]);
            ah1.u[j] = (ushort)(w >> 16);
            al1.u[j] = (ushort)(__float_as_uint(xv[8 + j] - __uint_as_float(w & 0xffff0000u)) >> 16);
        }

        // ---- prefetch next iter's A ----
        if (k0 + 64 < K) {
            const float* ap = xrow + k0 + 64;
            xa0 = *(const float4*)(ap);
            xa1 = *(const float4*)(ap + 4);
            xb0 = *(const float4*)(ap + 32);
            xb1 = *(const float4*)(ap + 36);
        }

        // ---- tile-pipelined B: load t+1 while MFMA t ----
        LOADB1(kb, tb + 1);
        MFMA6(b00, b01, b02, b03, 0);
        LOADB0(kb, tb + 2);
        MFMA6(b10, b11, b12, b13, 1);
        LOADB1(kb, tb + 3);
        MFMA6(b00, b01, b02, b03, 2);
        if (k0 + 64 < K) LOADB0(kb + 1, tb);
        MFMA6(b10, b11, b12, b13, 3);
    }

    // ---- epilogue: D(lane,reg): m = bm + g*16 + kq*4 + r, n = (ch*4+t)*16 + fr ----
#pragma unroll
    for (int r = 0; r < 4; ++r) {
        const int m = bm + g * 16 + kq * 4 + r;
        if (m < NN) {
            const float dv = dinv[m];
            const float d2 = dv * dv;
            ushort* om = out_main + (size_t)m * C_HID;
            float* os = out_self + (size_t)m * C_HID;
#pragma unroll
            for (int t = 0; t < 4; ++t) {
                const int n = (ch * 4 + t) * 16 + fr;
                const float v = acc[t][r];
                om[n] = f2bf(v);
                os[n] = v * d2 + (OUT_BIAS ? bout[n] : 0.f);
            }
        }
    }
}

// ---------------- CSR gather: out[d] = init(out[d]) + sum_e bf16(h[src_e])*norm_e ----------------
__global__ __launch_bounds__(256) void k_gather(const ushort* __restrict__ h,
                                                const int* __restrict__ rowptr,
                                                const uint* __restrict__ csr,
                                                float* __restrict__ out) {
    const int tid = threadIdx.x;
    const int node = blockIdx.x * 8 + (tid >> 5);
    if (node >= NN) return;
    const int lane = tid & 31;
    const int c = lane * 4;
    const int beg = rowptr[node];
    const int end = rowptr[node + 1];

    float4 acc = *(const float4*)(out + (size_t)node * C_HID + c);  // self-loop init

    for (int j0 = beg; j0 < end; j0 += 32) {
        const int n = end - j0;
        uint myE = 0;
        if (lane < n) myE = csr[j0 + lane];
        const int m = n < 32 ? n : 32;
        int jj = 0;
        for (; jj + 4 <= m; jj += 4) {
            const uint e0 = (uint)__shfl((int)myE, jj + 0, 32);
            const uint e1 = (uint)__shfl((int)myE, jj + 1, 32);
            const uint e2 = (uint)__shfl((int)myE, jj + 2, 32);
            const uint e3 = (uint)__shfl((int)myE, jj + 3, 32);
            const us4 u0 = *(const us4*)(h + (size_t)(e0 >> 16) * C_HID + c);
            const us4 u1 = *(const us4*)(h + (size_t)(e1 >> 16) * C_HID + c);
            const us4 u2 = *(const us4*)(h + (size_t)(e2 >> 16) * C_HID + c);
            const us4 u3 = *(const us4*)(h + (size_t)(e3 >> 16) * C_HID + c);
            const float n0 = __half2float(__ushort_as_half((ushort)(e0 & 0xffffu)));
            const float n1 = __half2float(__ushort_as_half((ushort)(e1 & 0xffffu)));
            const float n2 = __half2float(__ushort_as_half((ushort)(e2 & 0xffffu)));
            const float n3 = __half2float(__ushort_as_half((ushort)(e3 & 0xffffu)));
            acc.x = fmaf(bf2f(u0[0]), n0, acc.x);
            acc.y = fmaf(bf2f(u0[1]), n0, acc.y);
            acc.z = fmaf(bf2f(u0[2]), n0, acc.z);
            acc.w = fmaf(bf2f(u0[3]), n0, acc.w);
            acc.x = fmaf(bf2f(u1[0]), n1, acc.x);
            acc.y = fmaf(bf2f(u1[1]), n1, acc.y);
            acc.z = fmaf(bf2f(u1[2]), n1, acc.z);
            acc.w = fmaf(bf2f(u1[3]), n1, acc.w);
            acc.x = fmaf(bf2f(u2[0]), n2, acc.x);
            acc.y = fmaf(bf2f(u2[1]), n2, acc.y);
            acc.z = fmaf(bf2f(u2[2]), n2, acc.z);
            acc.w = fmaf(bf2f(u2[3]), n2, acc.w);
            acc.x = fmaf(bf2f(u3[0]), n3, acc.x);
            acc.y = fmaf(bf2f(u3[1]), n3, acc.y);
            acc.z = fmaf(bf2f(u3[2]), n3, acc.z);
            acc.w = fmaf(bf2f(u3[3]), n3, acc.w);
        }
        for (; jj < m; ++jj) {
            const uint ev = (uint)__shfl((int)myE, jj, 32);
            const us4 u = *(const us4*)(h + (size_t)(ev >> 16) * C_HID + c);
            const float nw = __half2float(__ushort_as_half((ushort)(ev & 0xffffu)));
            acc.x = fmaf(bf2f(u[0]), nw, acc.x);
            acc.y = fmaf(bf2f(u[1]), nw, acc.y);
            acc.z = fmaf(bf2f(u[2]), nw, acc.z);
            acc.w = fmaf(bf2f(u[3]), nw, acc.w);
        }
    }
    *(float4*)(out + (size_t)node * C_HID + c) = acc;
}

extern "C" void kernel_launch(void* const* d_in, const int* in_sizes, int n_in,
                              void* d_out, int out_size, void* d_ws, size_t ws_size,
                              hipStream_t stream) {
    const float* x = (const float*)d_in[0];
    const int* ei = (const int*)d_in[1];
    const float* W1 = (const float*)d_in[2];
    const float* b1 = (const float*)d_in[3];
    const float* W2 = (const float*)d_in[4];
    const float* b2 = (const float*)d_in[5];
    float* out = (float*)d_out;

    const int* src = ei;
    const int* dst = ei + NE;

    // workspace layout (4-byte units)
    int* cnt = (int*)d_ws;                       // 50048
    int* rowptr = cnt + 50048;                   // 50064 (NN+1)
    float* dinv = (float*)(rowptr + 50064);      // 50048
    int* bsum = (int*)(dinv + 50048);            // 256
    int* bpre = bsum + 256;                      // 256
    int* histT = bpre + 256;                     // 16384
    int* histS = histT + 16384;                  // 16384
    ushort* Wt1 = (ushort*)(histS + 16384);      // 98304 shorts (frag-linear hi+lo)
    ushort* Wt2 = Wt1 + 98304;                   // 32768 shorts
    uint* csr = (uint*)(Wt2 + 32768);            // NE uints
    uint2* mid = (uint2*)(csr + NE);             // NE uint2
    ushort* A_bf = (ushort*)(mid + NE);          // NN*128 shorts (h bf16)
    float* B = (float*)(A_bf + (size_t)NN * C_HID);  // NN*128 fp32 (agg buffer)

    k_wconv<<<(C_IN * C_HID + 255) / 256, 256, 0, stream>>>(W1, Wt1, C_IN);
    k_wconv<<<(C_HID * C_HID + 255) / 256, 256, 0, stream>>>(W2, Wt2, C_HID);
    k_hist<<<CHK, 256, 0, stream>>>(dst, histT);
    k_hscan<<<1, 1024, 0, stream>>>(histT, histS);
    k_binscat<<<CHK, 256, 0, stream>>>(src, dst, histS, mid);
    k_bcnt<<<NBKT, 256, 0, stream>>>(mid, histS, cnt);
    k_dinv<<<NB, 256, 0, stream>>>(cnt, dinv);
    k_bsum<<<NB, 256, 0, stream>>>(cnt, bsum);
    k_sbs<<<1, 256, 0, stream>>>(bsum, bpre);
    k_write<<<NB, 256, 0, stream>>>(cnt, bpre, rowptr);
    k_binfill<<<NBKT, 256, 0, stream>>>(mid, histS, rowptr, dinv, csr);

    const int gblocks = (NN + 31) / 32;
    const int agblocks = (NN + 7) / 8;
    // layer 1: h1 = x@W1 -> A_bf (bf16) ;  B = h1*dinv^2 (fp32 self-loop init)
    k_gemm_mfma<false, false><<<gblocks, 256, 0, stream>>>(x, Wt1, nullptr, nullptr, dinv, A_bf, B, C_IN);
    // B += gather(h1)
    k_gather<<<agblocks, 256, 0, stream>>>(A_bf, rowptr, csr, B);
    // layer 2: h2 = relu(B + b1)@W2 -> A_bf ; out = h2*dinv^2 + b2 (self-loop init)
    k_gemm_mfma<true, true><<<gblocks, 256, 0, stream>>>(B, Wt2, b1, b2, dinv, A_bf, out, C_HID);
    // out += gather(h2)
    k_gather<<<agblocks, 256, 0, stream>>>(A_bf, rowptr, csr, out);
}

// Round 5
// 316.078 us; speedup vs baseline: 1.1221x; 1.0320x over previous
//
#include <hip/hip_runtime.h>
#include <hip/hip_fp16.h>

#define NN 50000
#define NE 800000
#define C_IN 384
#define C_HID 128
#define NB 196    // ceil(NN/256)
#define CHK 128   // edge chunks
#define ECH 6250  // edges per chunk (128*6250 = 800000)
#define NBKT 128  // dst buckets
#define BSTR 392  // dst stride per bucket (128*392 = 50176 >= NN)

typedef __attribute__((ext_vector_type(8))) short short8;
typedef __attribute__((ext_vector_type(4))) float f32x4;
typedef __attribute__((ext_vector_type(4))) unsigned short us4;

__device__ __forceinline__ ushort f2bf(float x) {
    uint u = __float_as_uint(x);
    uint r = (u + 0x7fffu + ((u >> 16) & 1u)) >> 16;  // RNE
    return (ushort)r;
}
__device__ __forceinline__ float bf2f(ushort b) { return __uint_as_float(((uint)b) << 16); }

__global__ __launch_bounds__(256) void k_dinv(const int* __restrict__ cnt,
                                              float* __restrict__ dinv) {
    int i = blockIdx.x * 256 + threadIdx.x;
    if (i < NN) dinv[i] = rsqrtf((float)cnt[i] + 1.0f);  // +1 = self loop
}

// ---------------- hierarchical exclusive scan over NN counts -> rowptr ----------------
__global__ __launch_bounds__(256) void k_bsum(const int* __restrict__ cnt,
                                              int* __restrict__ bsum) {
    __shared__ int part[256];
    const int tid = threadIdx.x;
    const int i = blockIdx.x * 256 + tid;
    part[tid] = (i < NN) ? cnt[i] : 0;
    __syncthreads();
#pragma unroll
    for (int off = 128; off > 0; off >>= 1) {
        if (tid < off) part[tid] += part[tid + off];
        __syncthreads();
    }
    if (tid == 0) bsum[blockIdx.x] = part[0];
}

__global__ __launch_bounds__(256) void k_sbs(const int* __restrict__ bsum,
                                             int* __restrict__ bpre) {
    __shared__ int part[256];
    const int t = threadIdx.x;
    part[t] = (t < NB) ? bsum[t] : 0;
    __syncthreads();
#pragma unroll
    for (int off = 1; off < 256; off <<= 1) {
        int v = (t >= off) ? part[t - off] : 0;
        __syncthreads();
        part[t] += v;
        __syncthreads();
    }
    if (t < NB) bpre[t] = (t == 0) ? 0 : part[t - 1];  // exclusive
}

__global__ __launch_bounds__(256) void k_write(const int* __restrict__ cnt,
                                               const int* __restrict__ bpre,
                                               int* __restrict__ rowptr) {
    __shared__ int part[256];
    const int t = threadIdx.x;
    const int i = blockIdx.x * 256 + t;
    const int v = (i < NN) ? cnt[i] : 0;
    part[t] = v;
    __syncthreads();
#pragma unroll
    for (int off = 1; off < 256; off <<= 1) {
        int u = (t >= off) ? part[t - off] : 0;
        __syncthreads();
        part[t] += u;
        __syncthreads();
    }
    if (i < NN) {
        const int excl = bpre[blockIdx.x] + part[t] - v;
        rowptr[i] = excl;
        if (i == NN - 1) rowptr[NN] = excl + v;
    }
}

// ---------------- bucket pipeline: hist -> hscan -> binscat -> bcnt -> binfill ----------------
__global__ __launch_bounds__(256) void k_hist(const int* __restrict__ dst,
                                              int* __restrict__ histT) {
    __shared__ int h[NBKT];
    const int tid = threadIdx.x;
    if (tid < NBKT) h[tid] = 0;
    __syncthreads();
    const int base = blockIdx.x * ECH;
    for (int i = base + tid; i < base + ECH; i += 256)
        atomicAdd(&h[(uint)dst[i] / BSTR], 1);
    __syncthreads();
    if (tid < NBKT) histT[tid * CHK + blockIdx.x] = h[tid];
}

__global__ __launch_bounds__(1024) void k_hscan(const int* __restrict__ histT,
                                                int* __restrict__ histS) {
    __shared__ int part[1024];
    const int t = threadIdx.x;
    const int base = t * 16;
    int loc[16];
    int s = 0;
#pragma unroll
    for (int i = 0; i < 16; ++i) {
        loc[i] = histT[base + i];
        s += loc[i];
    }
    part[t] = s;
    __syncthreads();
    for (int off = 1; off < 1024; off <<= 1) {
        int v = (t >= off) ? part[t - off] : 0;
        __syncthreads();
        part[t] += v;
        __syncthreads();
    }
    int run = (t == 0) ? 0 : part[t - 1];
#pragma unroll
    for (int i = 0; i < 16; ++i) {
        histS[base + i] = run;
        run += loc[i];
    }
}

// k_binscat: chunks re-read edges, write (dst, src<<16) to bucket-major mid[]
__global__ __launch_bounds__(256) void k_binscat(const int* __restrict__ src,
                                                 const int* __restrict__ dst,
                                                 const int* __restrict__ histS,
                                                 uint2* __restrict__ mid) {
    __shared__ int cur[NBKT];
    const int tid = threadIdx.x;
    if (tid < NBKT) cur[tid] = histS[tid * CHK + blockIdx.x];
    __syncthreads();
    const int base = blockIdx.x * ECH;
    for (int i = base + tid; i < base + ECH; i += 256) {
        const int s = src[i];
        const int d = dst[i];
        const int p = atomicAdd(&cur[(uint)d / BSTR], 1);
        mid[p] = make_uint2((uint)d, (uint)s << 16);
    }
}

// k_bcnt: per-node degree counts from bucketed mid (replaces global atomic k_deg)
__global__ __launch_bounds__(256) void k_bcnt(const uint2* __restrict__ mid,
                                              const int* __restrict__ histS,
                                              int* __restrict__ cnt) {
    __shared__ int cur[BSTR];
    const int tid = threadIdx.x;
    const int b = blockIdx.x;
    for (int j = tid; j < BSTR; j += 256) cur[j] = 0;
    __syncthreads();
    const int lo = histS[b * CHK];
    const int hi = (b < NBKT - 1) ? histS[(b + 1) * CHK] : NE;
    for (int e = lo + tid; e < hi; e += 256)
        atomicAdd(&cur[mid[e].x - (uint)b * BSTR], 1);
    __syncthreads();
    for (int j = tid; j < BSTR; j += 256) {
        const int idx = b * BSTR + j;
        if (idx < NN) cnt[idx] = cur[j];
    }
}

// k_binfill: one block per bucket; computes norm, scatter confined to ~25 KB csr window
__global__ __launch_bounds__(256) void k_binfill(const uint2* __restrict__ mid,
                                                 const int* __restrict__ histS,
                                                 const int* __restrict__ rowptr,
                                                 const float* __restrict__ dinv,
                                                 uint* __restrict__ csr) {
    __shared__ int cur[BSTR];
    __shared__ float sdv[BSTR];
    const int tid = threadIdx.x;
    const int b = blockIdx.x;
    for (int j = tid; j < BSTR; j += 256) {
        const int idx = b * BSTR + j;
        cur[j] = (idx < NN) ? rowptr[idx] : 0;
        sdv[j] = (idx < NN) ? dinv[idx] : 0.f;
    }
    __syncthreads();
    const int lo = histS[b * CHK];
    const int hi = (b < NBKT - 1) ? histS[(b + 1) * CHK] : NE;
    for (int e = lo + tid; e < hi; e += 256) {
        const uint2 u = mid[e];
        const int j = u.x - (uint)b * BSTR;
        const float norm = dinv[u.y >> 16] * sdv[j];
        const int p = atomicAdd(&cur[j], 1);
        csr[p] = u.y | __half_as_ushort(__float2half(norm));
    }
}

// ---------------- W -> fragment-linear hi/lo bf16 split (once per launch) ----------------
__global__ __launch_bounds__(256) void k_wconv(const float* __restrict__ W,
                                               ushort* __restrict__ Wt,
                                               int K) {
    int i = blockIdx.x * 256 + threadIdx.x;
    if (i < K * C_HID) {
        int k = i >> 7, n = i & 127;  // N = 128
        float w = W[i];
        ushort h = f2bf(w);
        ushort l = f2bf(w - bf2f(h));
        int blk = k >> 6, khalf = (k >> 5) & 1, kq = (k >> 3) & 3, j = k & 7;
        int t = n >> 4, fr = n & 15, lane = kq * 16 + fr;
        size_t off = (size_t)blk * 16384 + (size_t)((khalf * 8 + t) * 64 + lane) * 8 + j;
        Wt[off] = h;
        Wt[off + 8192] = l;
    }
}

// ---------------- split-bf16 MFMA GEMM, BM=32, LDS double-buffer, vmcnt-preserving barrier ----
// 4 waves: g = wv>>1 -> rows [bm+g*16, +16); ch = wv&1 -> col tiles [ch*4, ch*4+4)
// Per k-block: issue W(kb+1)->regs first, conv A(kb), reload A(kb+2) (2-deep, covers HBM),
// MFMA from LDS buf[kb&1], ds_write W(kb+1)->buf[(kb+1)&1], then lgkmcnt(0)-only barrier
// (NO vmcnt drain -> A prefetch stays in flight across the barrier).
template <bool IN_RELU_BIAS, bool OUT_BIAS>
__global__ __launch_bounds__(256) void k_gemm_mfma(const float* __restrict__ X,
                                                   const ushort* __restrict__ Wt,
                                                   const float* __restrict__ bin,
                                                   const float* __restrict__ bout,
                                                   const float* __restrict__ dinv,
                                                   ushort* __restrict__ out_main,
                                                   float* __restrict__ out_self,
                                                   int K) {
    __shared__ short8 Bs8[2][2048];  // 2 x 32 KB double buffer

    const int tid = threadIdx.x;
    const int bm = blockIdx.x * 32;
    const int wv = tid >> 6;
    const int lane = tid & 63;
    const int fr = lane & 15;
    const int kq = lane >> 4;
    const int g = wv >> 1;
    const int ch = wv & 1;

    int row = bm + g * 16 + fr;
    if (row >= NN) row = NN - 1;  // clamp (stores guarded)
    const float* xrow = X + (size_t)row * K + kq * 8;
    const short8* Wt8 = (const short8*)Wt;
    const int NK = K >> 6;  // 6 (K=384) or 2 (K=128) -- always even

    f32x4 acc[4];
#pragma unroll
    for (int t = 0; t < 4; ++t) acc[t] = (f32x4){0.f, 0.f, 0.f, 0.f};

    // ---- prologue: W(0)->tmp->LDS buf0; A(0)->set0, A(1)->set1 ----
    short8 tmp[8];
#pragma unroll
    for (int i = 0; i < 8; ++i) tmp[i] = Wt8[i * 256 + tid];
    float4 a00 = *(const float4*)(xrow);
    float4 a01 = *(const float4*)(xrow + 4);
    float4 a02 = *(const float4*)(xrow + 32);
    float4 a03 = *(const float4*)(xrow + 36);
    const float* ap1 = xrow + 64;  // NK >= 2 always
    float4 a10 = *(const float4*)(ap1);
    float4 a11 = *(const float4*)(ap1 + 4);
    float4 a12 = *(const float4*)(ap1 + 32);
    float4 a13 = *(const float4*)(ap1 + 36);
#pragma unroll
    for (int i = 0; i < 8; ++i) Bs8[0][i * 256 + tid] = tmp[i];
    asm volatile("s_waitcnt lgkmcnt(0)" ::: "memory");
    __builtin_amdgcn_s_barrier();

    auto ITER = [&](int kb, float4& A0, float4& A1, float4& A2, float4& A3) {
        const bool nxt = (kb + 1 < NK);
        // 1) issue W(kb+1) loads first (max latency cover before ds_write's vmcnt wait)
        if (nxt) {
            const short8* gW = Wt8 + (size_t)(kb + 1) * 2048;
#pragma unroll
            for (int i = 0; i < 8; ++i) tmp[i] = gW[i * 256 + tid];
        }
        // 2) convert A(kb) to hi/lo bf16 frags
        float xv[16] = {A0.x, A0.y, A0.z, A0.w, A1.x, A1.y, A1.z, A1.w,
                        A2.x, A2.y, A2.z, A2.w, A3.x, A3.y, A3.z, A3.w};
        if (IN_RELU_BIAS) {
            const float* bp = bin + kb * 64 + kq * 8;
            float4 c0 = *(const float4*)(bp);
            float4 c1 = *(const float4*)(bp + 4);
            float4 c2 = *(const float4*)(bp + 32);
            float4 c3 = *(const float4*)(bp + 36);
            const float bb[16] = {c0.x, c0.y, c0.z, c0.w, c1.x, c1.y, c1.z, c1.w,
                                  c2.x, c2.y, c2.z, c2.w, c3.x, c3.y, c3.z, c3.w};
#pragma unroll
            for (int j = 0; j < 16; ++j) xv[j] = fmaxf(xv[j] + bb[j], 0.f);
        }
        union { ushort u[8]; short8 v; } ah0, al0, ah1, al1;
#pragma unroll
        for (int j = 0; j < 8; ++j) {
            uint u = __float_as_uint(xv[j]);
            ah0.u[j] = (ushort)(u >> 16);
            al0.u[j] = (ushort)(__float_as_uint(xv[j] - __uint_as_float(u & 0xffff0000u)) >> 16);
            uint w = __float_as_uint(xv[8 + j]);
            ah1.u[j] = (ushort)(w >> 16);
            al1.u[j] = (ushort)(__float_as_uint(xv[8 + j] - __uint_as_float(w & 0xffff0000u)) >> 16);
        }
        // 3) reload this A-set with A(kb+2) (consumed two iterations from now)
        if (kb + 2 < NK) {
            const float* ap = xrow + (kb + 2) * 64;
            A0 = *(const float4*)(ap);
            A1 = *(const float4*)(ap + 4);
            A2 = *(const float4*)(ap + 32);
            A3 = *(const float4*)(ap + 36);
        }
        // 4) MFMA from LDS buf[kb&1]
        const short8* bs = Bs8[kb & 1];
#pragma unroll
        for (int t = 0; t < 4; ++t) {
            const int tt = ch * 4 + t;
            const short8 bh0 = bs[tt * 64 + lane];
            const short8 bl0 = bs[1024 + tt * 64 + lane];
            const short8 bh1 = bs[(8 + tt) * 64 + lane];
            const short8 bl1 = bs[1024 + (8 + tt) * 64 + lane];
            acc[t] = __builtin_amdgcn_mfma_f32_16x16x32_bf16(ah0.v, bh0, acc[t], 0, 0, 0);
            acc[t] = __builtin_amdgcn_mfma_f32_16x16x32_bf16(ah0.v, bl0, acc[t], 0, 0, 0);
            acc[t] = __builtin_amdgcn_mfma_f32_16x16x32_bf16(al0.v, bh0, acc[t], 0, 0, 0);
            acc[t] = __builtin_amdgcn_mfma_f32_16x16x32_bf16(ah1.v, bh1, acc[t], 0, 0, 0);
            acc[t] = __builtin_amdgcn_mfma_f32_16x16x32_bf16(ah1.v, bl1, acc[t], 0, 0, 0);
            acc[t] = __builtin_amdgcn_mfma_f32_16x16x32_bf16(al1.v, bh1, acc[t], 0, 0, 0);
        }
        // 5) stage W(kb+1) into the other buffer; barrier WITHOUT vmcnt drain
        if (nxt) {
#pragma unroll
            for (int i = 0; i < 8; ++i) Bs8[(kb + 1) & 1][i * 256 + tid] = tmp[i];
            asm volatile("s_waitcnt lgkmcnt(0)" ::: "memory");
            __builtin_amdgcn_s_barrier();
        }
    };

    for (int kb = 0; kb < NK; kb += 2) {
        ITER(kb, a00, a01, a02, a03);
        ITER(kb + 1, a10, a11, a12, a13);
    }

    // ---- epilogue: D(lane,reg): m = bm + g*16 + kq*4 + r, n = (ch*4+t)*16 + fr ----
#pragma unroll
    for (int r = 0; r < 4; ++r) {
        const int m = bm + g * 16 + kq * 4 + r;
        if (m < NN) {
            const float dv = dinv[m];
            const float d2 = dv * dv;
            ushort* om = out_main + (size_t)m * C_HID;
            float* os = out_self + (size_t)m * C_HID;
#pragma unroll
            for (int t = 0; t < 4; ++t) {
                const int n = (ch * 4 + t) * 16 + fr;
                const float v = acc[t][r];
                om[n] = f2bf(v);
                os[n] = v * d2 + (OUT_BIAS ? bout[n] : 0.f);
            }
        }
    }
}

// ---------------- CSR gather: out[d] = init(out[d]) + sum_e bf16(h[src_e])*norm_e ----------------
__global__ __launch_bounds__(256) void k_gather(const ushort* __restrict__ h,
                                                const int* __restrict__ rowptr,
                                                const uint* __restrict__ csr,
                                                float* __restrict__ out) {
    const int tid = threadIdx.x;
    const int node = blockIdx.x * 8 + (tid >> 5);
    if (node >= NN) return;
    const int lane = tid & 31;
    const int c = lane * 4;
    const int beg = rowptr[node];
    const int end = rowptr[node + 1];

    float4 acc = *(const float4*)(out + (size_t)node * C_HID + c);  // self-loop init

    for (int j0 = beg; j0 < end; j0 += 32) {
        const int n = end - j0;
        uint myE = 0;
        if (lane < n) myE = csr[j0 + lane];
        const int m = n < 32 ? n : 32;
        int jj = 0;
        for (; jj + 4 <= m; jj += 4) {
            const uint e0 = (uint)__shfl((int)myE, jj + 0, 32);
            const uint e1 = (uint)__shfl((int)myE, jj + 1, 32);
            const uint e2 = (uint)__shfl((int)myE, jj + 2, 32);
            const uint e3 = (uint)__shfl((int)myE, jj + 3, 32);
            const us4 u0 = *(const us4*)(h + (size_t)(e0 >> 16) * C_HID + c);
            const us4 u1 = *(const us4*)(h + (size_t)(e1 >> 16) * C_HID + c);
            const us4 u2 = *(const us4*)(h + (size_t)(e2 >> 16) * C_HID + c);
            const us4 u3 = *(const us4*)(h + (size_t)(e3 >> 16) * C_HID + c);
            const float n0 = __half2float(__ushort_as_half((ushort)(e0 & 0xffffu)));
            const float n1 = __half2float(__ushort_as_half((ushort)(e1 & 0xffffu)));
            const float n2 = __half2float(__ushort_as_half((ushort)(e2 & 0xffffu)));
            const float n3 = __half2float(__ushort_as_half((ushort)(e3 & 0xffffu)));
            acc.x = fmaf(bf2f(u0[0]), n0, acc.x);
            acc.y = fmaf(bf2f(u0[1]), n0, acc.y);
            acc.z = fmaf(bf2f(u0[2]), n0, acc.z);
            acc.w = fmaf(bf2f(u0[3]), n0, acc.w);
            acc.x = fmaf(bf2f(u1[0]), n1, acc.x);
            acc.y = fmaf(bf2f(u1[1]), n1, acc.y);
            acc.z = fmaf(bf2f(u1[2]), n1, acc.z);
            acc.w = fmaf(bf2f(u1[3]), n1, acc.w);
            acc.x = fmaf(bf2f(u2[0]), n2, acc.x);
            acc.y = fmaf(bf2f(u2[1]), n2, acc.y);
            acc.z = fmaf(bf2f(u2[2]), n2, acc.z);
            acc.w = fmaf(bf2f(u2[3]), n2, acc.w);
            acc.x = fmaf(bf2f(u3[0]), n3, acc.x);
            acc.y = fmaf(bf2f(u3[1]), n3, acc.y);
            acc.z = fmaf(bf2f(u3[2]), n3, acc.z);
            acc.w = fmaf(bf2f(u3[3]), n3, acc.w);
        }
        for (; jj < m; ++jj) {
            const uint ev = (uint)__shfl((int)myE, jj, 32);
            const us4 u = *(const us4*)(h + (size_t)(ev >> 16) * C_HID + c);
            const float nw = __half2float(__ushort_as_half((ushort)(ev & 0xffffu)));
            acc.x = fmaf(bf2f(u[0]), nw, acc.x);
            acc.y = fmaf(bf2f(u[1]), nw, acc.y);
            acc.z = fmaf(bf2f(u[2]), nw, acc.z);
            acc.w = fmaf(bf2f(u[3]), nw, acc.w);
        }
    }
    *(float4*)(out + (size_t)node * C_HID + c) = acc;
}

extern "C" void kernel_launch(void* const* d_in, const int* in_sizes, int n_in,
                              void* d_out, int out_size, void* d_ws, size_t ws_size,
                              hipStream_t stream) {
    const float* x = (const float*)d_in[0];
    const int* ei = (const int*)d_in[1];
    const float* W1 = (const float*)d_in[2];
    const float* b1 = (const float*)d_in[3];
    const float* W2 = (const float*)d_in[4];
    const float* b2 = (const float*)d_in[5];
    float* out = (float*)d_out;

    const int* src = ei;
    const int* dst = ei + NE;

    // workspace layout (4-byte units)
    int* cnt = (int*)d_ws;                       // 50048
    int* rowptr = cnt + 50048;                   // 50064 (NN+1)
    float* dinv = (float*)(rowptr + 50064);      // 50048
    int* bsum = (int*)(dinv + 50048);            // 256
    int* bpre = bsum + 256;                      // 256
    int* histT = bpre + 256;                     // 16384
    int* histS = histT + 16384;                  // 16384
    ushort* Wt1 = (ushort*)(histS + 16384);      // 98304 shorts (frag-linear hi+lo)
    ushort* Wt2 = Wt1 + 98304;                   // 32768 shorts
    uint* csr = (uint*)(Wt2 + 32768);            // NE uints
    uint2* mid = (uint2*)(csr + NE);             // NE uint2
    ushort* A_bf = (ushort*)(mid + NE);          // NN*128 shorts (h bf16)
    float* B = (float*)(A_bf + (size_t)NN * C_HID);  // NN*128 fp32 (agg buffer)

    k_wconv<<<(C_IN * C_HID + 255) / 256, 256, 0, stream>>>(W1, Wt1, C_IN);
    k_wconv<<<(C_HID * C_HID + 255) / 256, 256, 0, stream>>>(W2, Wt2, C_HID);
    k_hist<<<CHK, 256, 0, stream>>>(dst, histT);
    k_hscan<<<1, 1024, 0, stream>>>(histT, histS);
    k_binscat<<<CHK, 256, 0, stream>>>(src, dst, histS, mid);
    k_bcnt<<<NBKT, 256, 0, stream>>>(mid, histS, cnt);
    k_dinv<<<NB, 256, 0, stream>>>(cnt, dinv);
    k_bsum<<<NB, 256, 0, stream>>>(cnt, bsum);
    k_sbs<<<1, 256, 0, stream>>>(bsum, bpre);
    k_write<<<NB, 256, 0, stream>>>(cnt, bpre, rowptr);
    k_binfill<<<NBKT, 256, 0, stream>>>(mid, histS, rowptr, dinv, csr);

    const int gblocks = (NN + 31) / 32;
    const int agblocks = (NN + 7) / 8;
    // layer 1: h1 = x@W1 -> A_bf (bf16) ;  B = h1*dinv^2 (fp32 self-loop init)
    k_gemm_mfma<false, false><<<gblocks, 256, 0, stream>>>(x, Wt1, nullptr, nullptr, dinv, A_bf, B, C_IN);
    // B += gather(h1)
    k_gather<<<agblocks, 256, 0, stream>>>(A_bf, rowptr, csr, B);
    // layer 2: h2 = relu(B + b1)@W2 -> A_bf ; out = h2*dinv^2 + b2 (self-loop init)
    k_gemm_mfma<true, true><<<gblocks, 256, 0, stream>>>(B, Wt2, b1, b2, dinv, A_bf, out, C_HID);
    // out += gather(h2)
    k_gather<<<agblocks, 256, 0, stream>>>(A_bf, rowptr, csr, out);
}

// Round 6
// 309.830 us; speedup vs baseline: 1.1447x; 1.0202x over previous
//
#include <hip/hip_runtime.h>
#include <hip/hip_fp16.h>

#define NN 50000
#define NE 800000
#define C_IN 384
#define C_HID 128
#define NB 196    // ceil(NN/256)
#define CHK 128   // edge chunks
#define ECH 6250  // edges per chunk (128*6250 = 800000)
#define NBKT 128  // dst buckets
#define BSTR 392  // dst stride per bucket (128*392 = 50176 >= NN)

typedef __attribute__((ext_vector_type(8))) short short8;
typedef __attribute__((ext_vector_type(4))) float f32x4;
typedef __attribute__((ext_vector_type(4))) unsigned short us4;

__device__ __forceinline__ ushort f2bf(float x) {
    uint u = __float_as_uint(x);
    uint r = (u + 0x7fffu + ((u >> 16) & 1u)) >> 16;  // RNE
    return (ushort)r;
}
__device__ __forceinline__ float bf2f(ushort b) { return __uint_as_float(((uint)b) << 16); }

typedef __attribute__((address_space(1))) const unsigned int as1_uint;
typedef __attribute__((address_space(3))) unsigned int as3_uint;
__device__ __forceinline__ void gload16(const void* g, void* l) {
    __builtin_amdgcn_global_load_lds((as1_uint*)g, (as3_uint*)l, 16, 0, 0);
}

__global__ __launch_bounds__(256) void k_dinv(const int* __restrict__ cnt,
                                              float* __restrict__ dinv) {
    int i = blockIdx.x * 256 + threadIdx.x;
    if (i < NN) dinv[i] = rsqrtf((float)cnt[i] + 1.0f);  // +1 = self loop
}

// ---------------- hierarchical exclusive scan over NN counts -> rowptr ----------------
__global__ __launch_bounds__(256) void k_bsum(const int* __restrict__ cnt,
                                              int* __restrict__ bsum) {
    __shared__ int part[256];
    const int tid = threadIdx.x;
    const int i = blockIdx.x * 256 + tid;
    part[tid] = (i < NN) ? cnt[i] : 0;
    __syncthreads();
#pragma unroll
    for (int off = 128; off > 0; off >>= 1) {
        if (tid < off) part[tid] += part[tid + off];
        __syncthreads();
    }
    if (tid == 0) bsum[blockIdx.x] = part[0];
}

__global__ __launch_bounds__(256) void k_sbs(const int* __restrict__ bsum,
                                             int* __restrict__ bpre) {
    __shared__ int part[256];
    const int t = threadIdx.x;
    part[t] = (t < NB) ? bsum[t] : 0;
    __syncthreads();
#pragma unroll
    for (int off = 1; off < 256; off <<= 1) {
        int v = (t >= off) ? part[t - off] : 0;
        __syncthreads();
        part[t] += v;
        __syncthreads();
    }
    if (t < NB) bpre[t] = (t == 0) ? 0 : part[t - 1];  // exclusive
}

__global__ __launch_bounds__(256) void k_write(const int* __restrict__ cnt,
                                               const int* __restrict__ bpre,
                                               int* __restrict__ rowptr) {
    __shared__ int part[256];
    const int t = threadIdx.x;
    const int i = blockIdx.x * 256 + t;
    const int v = (i < NN) ? cnt[i] : 0;
    part[t] = v;
    __syncthreads();
#pragma unroll
    for (int off = 1; off < 256; off <<= 1) {
        int u = (t >= off) ? part[t - off] : 0;
        __syncthreads();
        part[t] += u;
        __syncthreads();
    }
    if (i < NN) {
        const int excl = bpre[blockIdx.x] + part[t] - v;
        rowptr[i] = excl;
        if (i == NN - 1) rowptr[NN] = excl + v;
    }
}

// ---------------- bucket pipeline: hist -> hscan -> binscat -> bcnt -> binfill ----------------
__global__ __launch_bounds__(256) void k_hist(const int* __restrict__ dst,
                                              int* __restrict__ histT) {
    __shared__ int h[NBKT];
    const int tid = threadIdx.x;
    if (tid < NBKT) h[tid] = 0;
    __syncthreads();
    const int base = blockIdx.x * ECH;
    for (int i = base + tid; i < base + ECH; i += 256)
        atomicAdd(&h[(uint)dst[i] / BSTR], 1);
    __syncthreads();
    if (tid < NBKT) histT[tid * CHK + blockIdx.x] = h[tid];
}

__global__ __launch_bounds__(1024) void k_hscan(const int* __restrict__ histT,
                                                int* __restrict__ histS) {
    __shared__ int part[1024];
    const int t = threadIdx.x;
    const int base = t * 16;
    int loc[16];
    int s = 0;
#pragma unroll
    for (int i = 0; i < 16; ++i) {
        loc[i] = histT[base + i];
        s += loc[i];
    }
    part[t] = s;
    __syncthreads();
    for (int off = 1; off < 1024; off <<= 1) {
        int v = (t >= off) ? part[t - off] : 0;
        __syncthreads();
        part[t] += v;
        __syncthreads();
    }
    int run = (t == 0) ? 0 : part[t - 1];
#pragma unroll
    for (int i = 0; i < 16; ++i) {
        histS[base + i] = run;
        run += loc[i];
    }
}

// k_binscat: chunks re-read edges, write (dst, src<<16) to bucket-major mid[]
__global__ __launch_bounds__(256) void k_binscat(const int* __restrict__ src,
                                                 const int* __restrict__ dst,
                                                 const int* __restrict__ histS,
                                                 uint2* __restrict__ mid) {
    __shared__ int cur[NBKT];
    const int tid = threadIdx.x;
    if (tid < NBKT) cur[tid] = histS[tid * CHK + blockIdx.x];
    __syncthreads();
    const int base = blockIdx.x * ECH;
    for (int i = base + tid; i < base + ECH; i += 256) {
        const int s = src[i];
        const int d = dst[i];
        const int p = atomicAdd(&cur[(uint)d / BSTR], 1);
        mid[p] = make_uint2((uint)d, (uint)s << 16);
    }
}

// k_bcnt: per-node degree counts from bucketed mid (replaces global atomic k_deg)
__global__ __launch_bounds__(256) void k_bcnt(const uint2* __restrict__ mid,
                                              const int* __restrict__ histS,
                                              int* __restrict__ cnt) {
    __shared__ int cur[BSTR];
    const int tid = threadIdx.x;
    const int b = blockIdx.x;
    for (int j = tid; j < BSTR; j += 256) cur[j] = 0;
    __syncthreads();
    const int lo = histS[b * CHK];
    const int hi = (b < NBKT - 1) ? histS[(b + 1) * CHK] : NE;
    for (int e = lo + tid; e < hi; e += 256)
        atomicAdd(&cur[mid[e].x - (uint)b * BSTR], 1);
    __syncthreads();
    for (int j = tid; j < BSTR; j += 256) {
        const int idx = b * BSTR + j;
        if (idx < NN) cnt[idx] = cur[j];
    }
}

// k_binfill: one block per bucket; computes norm, scatter confined to ~25 KB csr window
__global__ __launch_bounds__(256) void k_binfill(const uint2* __restrict__ mid,
                                                 const int* __restrict__ histS,
                                                 const int* __restrict__ rowptr,
                                                 const float* __restrict__ dinv,
                                                 uint* __restrict__ csr) {
    __shared__ int cur[BSTR];
    __shared__ float sdv[BSTR];
    const int tid = threadIdx.x;
    const int b = blockIdx.x;
    for (int j = tid; j < BSTR; j += 256) {
        const int idx = b * BSTR + j;
        cur[j] = (idx < NN) ? rowptr[idx] : 0;
        sdv[j] = (idx < NN) ? dinv[idx] : 0.f;
    }
    __syncthreads();
    const int lo = histS[b * CHK];
    const int hi = (b < NBKT - 1) ? histS[(b + 1) * CHK] : NE;
    for (int e = lo + tid; e < hi; e += 256) {
        const uint2 u = mid[e];
        const int j = u.x - (uint)b * BSTR;
        const float norm = dinv[u.y >> 16] * sdv[j];
        const int p = atomicAdd(&cur[j], 1);
        csr[p] = u.y | __half_as_ushort(__float2half(norm));
    }
}

// ---------------- W -> fragment-linear hi/lo bf16 split, 32-k blocks ----------------
// per 32-k block: 1024 short8 = 16 KB; hi frags [0,512), lo frags [512,1024)
__global__ __launch_bounds__(256) void k_wconv(const float* __restrict__ W,
                                               ushort* __restrict__ Wt,
                                               int K) {
    int i = blockIdx.x * 256 + threadIdx.x;
    if (i < K * C_HID) {
        int k = i >> 7, n = i & 127;  // N = 128
        float w = W[i];
        ushort h = f2bf(w);
        ushort l = f2bf(w - bf2f(h));
        int blk = k >> 5, kq = (k >> 3) & 3, j = k & 7;
        int t = n >> 4, fr = n & 15, lane = kq * 16 + fr;
        size_t off = ((size_t)blk * 1024 + t * 64 + lane) * 8 + j;
        Wt[off] = h;
        Wt[off + 4096] = l;  // +512 short8
    }
}

// ---------------- split-bf16 MFMA GEMM, BM=64, 8 waves, K_STEP=32 ----------------
// X staged via LDS coalesced (16B-chunk XOR swizzle); W via async global_load_lds.
// Counted vmcnt(1) at barrier: per-thread VMEM/iter = {2 gload_lds, 1 X float4},
// issue-order pinned by sched_barrier(0) -> gloads complete, X prefetch stays in flight.
#define GEMM_BODY(KB, CUR, NXT, XOLD, XNEW)                                               \
    {                                                                                     \
        _Pragma("unroll")                                                                 \
        for (int i_ = 0; i_ < 2; ++i_)                                                    \
            gload16(Wt8 + (size_t)((KB) + 1) * 1024 + wv * 128 + i_ * 64 + lane,          \
                    &WL[NXT][wv * 128 + i_ * 64]);                                        \
        __builtin_amdgcn_sched_barrier(0);                                                \
        XNEW = *(const float4*)(xsrc + ((KB) + 2) * 32);                                  \
        *(float4*)(xdst[NXT]) = XOLD;                                                     \
        const float* xb_ = &XL[CUR][ar * 32];                                             \
        float4 xf0 = *(const float4*)(xb_ + ac0);                                         \
        float4 xf1 = *(const float4*)(xb_ + ac1);                                         \
        float xv[8] = {xf0.x, xf0.y, xf0.z, xf0.w, xf1.x, xf1.y, xf1.z, xf1.w};           \
        if (IN_RELU_BIAS) {                                                               \
            float4 b0 = *(const float4*)(&bias_lds[(KB) * 32 + kq * 8]);                  \
            float4 b1 = *(const float4*)(&bias_lds[(KB) * 32 + kq * 8 + 4]);              \
            const float bb[8] = {b0.x, b0.y, b0.z, b0.w, b1.x, b1.y, b1.z, b1.w};         \
            _Pragma("unroll")                                                             \
            for (int j_ = 0; j_ < 8; ++j_) xv[j_] = fmaxf(xv[j_] + bb[j_], 0.f);          \
        }                                                                                 \
        union { ushort u[8]; short8 v; } ah, al;                                          \
        _Pragma("unroll")                                                                 \
        for (int j_ = 0; j_ < 8; ++j_) {                                                  \
            uint u_ = __float_as_uint(xv[j_]);                                            \
            ah.u[j_] = (ushort)(u_ >> 16);                                                \
            al.u[j_] = (ushort)(__float_as_uint(xv[j_] - __uint_as_float(u_ & 0xffff0000u)) >> 16); \
        }                                                                                 \
        __builtin_amdgcn_s_setprio(1);                                                    \
        _Pragma("unroll")                                                                 \
        for (int t_ = 0; t_ < 4; ++t_) {                                                  \
            const int tt_ = ch * 4 + t_;                                                  \
            const short8 wh_ = WL[CUR][tt_ * 64 + lane];                                  \
            const short8 wl_ = WL[CUR][512 + tt_ * 64 + lane];                            \
            acc[t_] = __builtin_amdgcn_mfma_f32_16x16x32_bf16(ah.v, wh_, acc[t_], 0, 0, 0); \
            acc[t_] = __builtin_amdgcn_mfma_f32_16x16x32_bf16(ah.v, wl_, acc[t_], 0, 0, 0); \
            acc[t_] = __builtin_amdgcn_mfma_f32_16x16x32_bf16(al.v, wh_, acc[t_], 0, 0, 0); \
        }                                                                                 \
        __builtin_amdgcn_s_setprio(0);                                                    \
        __builtin_amdgcn_sched_barrier(0);                                                \
        asm volatile("s_waitcnt vmcnt(1) lgkmcnt(0)" ::: "memory");                       \
        __builtin_amdgcn_sched_barrier(0);                                                \
        __builtin_amdgcn_s_barrier();                                                     \
    }

template <bool IN_RELU_BIAS, bool OUT_BIAS>
__global__ __launch_bounds__(512) void k_gemm_mfma(const float* __restrict__ X,
                                                   const ushort* __restrict__ Wt,
                                                   const float* __restrict__ bin,
                                                   const float* __restrict__ bout,
                                                   const float* __restrict__ dinv,
                                                   ushort* __restrict__ out_main,
                                                   float* __restrict__ out_self,
                                                   int K) {
    __shared__ short8 WL[2][1024];   // 2 x 16 KB W double buffer (frag-linear)
    __shared__ float XL[2][2048];    // 2 x 8 KB X tile (64 rows x 32 cols, swizzled)
    __shared__ float bias_lds[128];

    const int tid = threadIdx.x;
    const int bm = blockIdx.x * 64;
    const int wv = tid >> 6;
    const int lane = tid & 63;
    const int fr = lane & 15;
    const int kq = lane >> 4;
    const int g = wv >> 1;   // 0..3 row-group
    const int ch = wv & 1;   // col half
    const int NK = K >> 5;   // 12 (K=384) or 4 (K=128) -- always even, >= 4

    const short8* Wt8 = (const short8*)Wt;

    // X staging: thread loads one float4, row-contiguous (coalesced)
    const int xr = tid >> 3;   // 0..63
    const int xc16 = tid & 7;  // 16B chunk within 128B row
    int xrow = bm + xr;
    if (xrow >= NN) xrow = NN - 1;
    const float* xsrc = X + (size_t)xrow * K + xc16 * 4;
    float* xdst[2] = {&XL[0][xr * 32 + ((xc16 ^ (xr & 7)) * 4)],
                      &XL[1][xr * 32 + ((xc16 ^ (xr & 7)) * 4)]};

    // A-fragment read addressing (swizzled chunks)
    const int ar = g * 16 + fr;  // 0..63 row within tile
    const int ac0 = ((2 * kq) ^ (ar & 7)) * 4;
    const int ac1 = ((2 * kq + 1) ^ (ar & 7)) * 4;

    f32x4 acc[4];
#pragma unroll
    for (int t = 0; t < 4; ++t) acc[t] = (f32x4){0.f, 0.f, 0.f, 0.f};

    if (IN_RELU_BIAS && tid < 128) bias_lds[tid] = bin[tid];

    // ---- prologue: W(0) -> WL[0] (async); X(0)->xA->XL[0]; X(1)->xB in flight ----
#pragma unroll
    for (int i_ = 0; i_ < 2; ++i_)
        gload16(Wt8 + (size_t)wv * 128 + i_ * 64 + lane, &WL[0][wv * 128 + i_ * 64]);
    __builtin_amdgcn_sched_barrier(0);
    float4 xA = *(const float4*)(xsrc);        // X(0)
    float4 xB = *(const float4*)(xsrc + 32);   // X(1)
    *(float4*)(xdst[0]) = xA;                  // auto-wait drains gloads + X(0); X(1) flies
    xA = xB;                                   // xA now holds X(1) = "old" entering iter 0
    asm volatile("s_waitcnt lgkmcnt(0)" ::: "memory");
    __builtin_amdgcn_sched_barrier(0);
    __builtin_amdgcn_s_barrier();

    // ---- main loop: kb = 0 .. NK-3 (NK-2 bodies, even count) ----
    for (int kb = 0; kb < NK - 2; kb += 2) {
        GEMM_BODY(kb, 0, 1, xA, xB);
        GEMM_BODY(kb + 1, 1, 0, xB, xA);
    }

    // ---- tail kb = NK-2 (CUR=0): last gloads, last ds_write, full drain ----
    {
        const int KB = NK - 2;
#pragma unroll
        for (int i_ = 0; i_ < 2; ++i_)
            gload16(Wt8 + (size_t)(KB + 1) * 1024 + wv * 128 + i_ * 64 + lane,
                    &WL[1][wv * 128 + i_ * 64]);
        *(float4*)(xdst[1]) = xA;  // X(NK-1)
        const float* xb_ = &XL[0][ar * 32];
        float4 xf0 = *(const float4*)(xb_ + ac0);
        float4 xf1 = *(const float4*)(xb_ + ac1);
        float xv[8] = {xf0.x, xf0.y, xf0.z, xf0.w, xf1.x, xf1.y, xf1.z, xf1.w};
        if (IN_RELU_BIAS) {
            float4 b0 = *(const float4*)(&bias_lds[KB * 32 + kq * 8]);
            float4 b1 = *(const float4*)(&bias_lds[KB * 32 + kq * 8 + 4]);
            const float bb[8] = {b0.x, b0.y, b0.z, b0.w, b1.x, b1.y, b1.z, b1.w};
#pragma unroll
            for (int j_ = 0; j_ < 8; ++j_) xv[j_] = fmaxf(xv[j_] + bb[j_], 0.f);
        }
        union { ushort u[8]; short8 v; } ah, al;
#pragma unroll
        for (int j_ = 0; j_ < 8; ++j_) {
            uint u_ = __float_as_uint(xv[j_]);
            ah.u[j_] = (ushort)(u_ >> 16);
            al.u[j_] = (ushort)(__float_as_uint(xv[j_] - __uint_as_float(u_ & 0xffff0000u)) >> 16);
        }
#pragma unroll
        for (int t_ = 0; t_ < 4; ++t_) {
            const int tt_ = ch * 4 + t_;
            const short8 wh_ = WL[0][tt_ * 64 + lane];
            const short8 wl_ = WL[0][512 + tt_ * 64 + lane];
            acc[t_] = __builtin_amdgcn_mfma_f32_16x16x32_bf16(ah.v, wh_, acc[t_], 0, 0, 0);
            acc[t_] = __builtin_amdgcn_mfma_f32_16x16x32_bf16(ah.v, wl_, acc[t_], 0, 0, 0);
            acc[t_] = __builtin_amdgcn_mfma_f32_16x16x32_bf16(al.v, wh_, acc[t_], 0, 0, 0);
        }
        __builtin_amdgcn_sched_barrier(0);
        asm volatile("s_waitcnt vmcnt(0) lgkmcnt(0)" ::: "memory");
        __builtin_amdgcn_sched_barrier(0);
        __builtin_amdgcn_s_barrier();
    }
    // ---- tail kb = NK-1 (CUR=1): compute only ----
    {
        const int KB = NK - 1;
        const float* xb_ = &XL[1][ar * 32];
        float4 xf0 = *(const float4*)(xb_ + ac0);
        float4 xf1 = *(const float4*)(xb_ + ac1);
        float xv[8] = {xf0.x, xf0.y, xf0.z, xf0.w, xf1.x, xf1.y, xf1.z, xf1.w};
        if (IN_RELU_BIAS) {
            float4 b0 = *(const float4*)(&bias_lds[KB * 32 + kq * 8]);
            float4 b1 = *(const float4*)(&bias_lds[KB * 32 + kq * 8 + 4]);
            const float bb[8] = {b0.x, b0.y, b0.z, b0.w, b1.x, b1.y, b1.z, b1.w};
#pragma unroll
            for (int j_ = 0; j_ < 8; ++j_) xv[j_] = fmaxf(xv[j_] + bb[j_], 0.f);
        }
        union { ushort u[8]; short8 v; } ah, al;
#pragma unroll
        for (int j_ = 0; j_ < 8; ++j_) {
            uint u_ = __float_as_uint(xv[j_]);
            ah.u[j_] = (ushort)(u_ >> 16);
            al.u[j_] = (ushort)(__float_as_uint(xv[j_] - __uint_as_float(u_ & 0xffff0000u)) >> 16);
        }
#pragma unroll
        for (int t_ = 0; t_ < 4; ++t_) {
            const int tt_ = ch * 4 + t_;
            const short8 wh_ = WL[1][tt_ * 64 + lane];
            const short8 wl_ = WL[1][512 + tt_ * 64 + lane];
            acc[t_] = __builtin_amdgcn_mfma_f32_16x16x32_bf16(ah.v, wh_, acc[t_], 0, 0, 0);
            acc[t_] = __builtin_amdgcn_mfma_f32_16x16x32_bf16(ah.v, wl_, acc[t_], 0, 0, 0);
            acc[t_] = __builtin_amdgcn_mfma_f32_16x16x32_bf16(al.v, wh_, acc[t_], 0, 0, 0);
        }
    }

    // ---- epilogue: D(lane,reg): m = bm + g*16 + kq*4 + r, n = (ch*4+t)*16 + fr ----
#pragma unroll
    for (int r = 0; r < 4; ++r) {
        const int m = bm + g * 16 + kq * 4 + r;
        if (m < NN) {
            const float dv = dinv[m];
            const float d2 = dv * dv;
            ushort* om = out_main + (size_t)m * C_HID;
            float* os = out_self + (size_t)m * C_HID;
#pragma unroll
            for (int t = 0; t < 4; ++t) {
                const int n = (ch * 4 + t) * 16 + fr;
                const float v = acc[t][r];
                om[n] = f2bf(v);
                os[n] = v * d2 + (OUT_BIAS ? bout[n] : 0.f);
            }
        }
    }
}

// ---------------- CSR gather: out[d] = init(out[d]) + sum_e bf16(h[src_e])*norm_e ----------------
__global__ __launch_bounds__(256) void k_gather(const ushort* __restrict__ h,
                                                const int* __restrict__ rowptr,
                                                const uint* __restrict__ csr,
                                                float* __restrict__ out) {
    const int tid = threadIdx.x;
    const int node = blockIdx.x * 8 + (tid >> 5);
    if (node >= NN) return;
    const int lane = tid & 31;
    const int c = lane * 4;
    const int beg = rowptr[node];
    const int end = rowptr[node + 1];

    float4 acc = *(const float4*)(out + (size_t)node * C_HID + c);  // self-loop init

    for (int j0 = beg; j0 < end; j0 += 32) {
        const int n = end - j0;
        uint myE = 0;
        if (lane < n) myE = csr[j0 + lane];
        const int m = n < 32 ? n : 32;
        int jj = 0;
        for (; jj + 4 <= m; jj += 4) {
            const uint e0 = (uint)__shfl((int)myE, jj + 0, 32);
            const uint e1 = (uint)__shfl((int)myE, jj + 1, 32);
            const uint e2 = (uint)__shfl((int)myE, jj + 2, 32);
            const uint e3 = (uint)__shfl((int)myE, jj + 3, 32);
            const us4 u0 = *(const us4*)(h + (size_t)(e0 >> 16) * C_HID + c);
            const us4 u1 = *(const us4*)(h + (size_t)(e1 >> 16) * C_HID + c);
            const us4 u2 = *(const us4*)(h + (size_t)(e2 >> 16) * C_HID + c);
            const us4 u3 = *(const us4*)(h + (size_t)(e3 >> 16) * C_HID + c);
            const float n0 = __half2float(__ushort_as_half((ushort)(e0 & 0xffffu)));
            const float n1 = __half2float(__ushort_as_half((ushort)(e1 & 0xffffu)));
            const float n2 = __half2float(__ushort_as_half((ushort)(e2 & 0xffffu)));
            const float n3 = __half2float(__ushort_as_half((ushort)(e3 & 0xffffu)));
            acc.x = fmaf(bf2f(u0[0]), n0, acc.x);
            acc.y = fmaf(bf2f(u0[1]), n0, acc.y);
            acc.z = fmaf(bf2f(u0[2]), n0, acc.z);
            acc.w = fmaf(bf2f(u0[3]), n0, acc.w);
            acc.x = fmaf(bf2f(u1[0]), n1, acc.x);
            acc.y = fmaf(bf2f(u1[1]), n1, acc.y);
            acc.z = fmaf(bf2f(u1[2]), n1, acc.z);
            acc.w = fmaf(bf2f(u1[3]), n1, acc.w);
            acc.x = fmaf(bf2f(u2[0]), n2, acc.x);
            acc.y = fmaf(bf2f(u2[1]), n2, acc.y);
            acc.z = fmaf(bf2f(u2[2]), n2, acc.z);
            acc.w = fmaf(bf2f(u2[3]), n2, acc.w);
            acc.x = fmaf(bf2f(u3[0]), n3, acc.x);
            acc.y = fmaf(bf2f(u3[1]), n3, acc.y);
            acc.z = fmaf(bf2f(u3[2]), n3, acc.z);
            acc.w = fmaf(bf2f(u3[3]), n3, acc.w);
        }
        for (; jj < m; ++jj) {
            const uint ev = (uint)__shfl((int)myE, jj, 32);
            const us4 u = *(const us4*)(h + (size_t)(ev >> 16) * C_HID + c);
            const float nw = __half2float(__ushort_as_half((ushort)(ev & 0xffffu)));
            acc.x = fmaf(bf2f(u[0]), nw, acc.x);
            acc.y = fmaf(bf2f(u[1]), nw, acc.y);
            acc.z = fmaf(bf2f(u[2]), nw, acc.z);
            acc.w = fmaf(bf2f(u[3]), nw, acc.w);
        }
    }
    *(float4*)(out + (size_t)node * C_HID + c) = acc;
}

extern "C" void kernel_launch(void* const* d_in, const int* in_sizes, int n_in,
                              void* d_out, int out_size, void* d_ws, size_t ws_size,
                              hipStream_t stream) {
    const float* x = (const float*)d_in[0];
    const int* ei = (const int*)d_in[1];
    const float* W1 = (const float*)d_in[2];
    const float* b1 = (const float*)d_in[3];
    const float* W2 = (const float*)d_in[4];
    const float* b2 = (const float*)d_in[5];
    float* out = (float*)d_out;

    const int* src = ei;
    const int* dst = ei + NE;

    // workspace layout (4-byte units)
    int* cnt = (int*)d_ws;                       // 50048
    int* rowptr = cnt + 50048;                   // 50064 (NN+1)
    float* dinv = (float*)(rowptr + 50064);      // 50048
    int* bsum = (int*)(dinv + 50048);            // 256
    int* bpre = bsum + 256;                      // 256
    int* histT = bpre + 256;                     // 16384
    int* histS = histT + 16384;                  // 16384
    ushort* Wt1 = (ushort*)(histS + 16384);      // 98304 shorts (frag-linear hi+lo)
    ushort* Wt2 = Wt1 + 98304;                   // 32768 shorts
    uint* csr = (uint*)(Wt2 + 32768);            // NE uints
    uint2* mid = (uint2*)(csr + NE);             // NE uint2
    ushort* A_bf = (ushort*)(mid + NE);          // NN*128 shorts (h bf16)
    float* B = (float*)(A_bf + (size_t)NN * C_HID);  // NN*128 fp32 (agg buffer)

    k_wconv<<<(C_IN * C_HID + 255) / 256, 256, 0, stream>>>(W1, Wt1, C_IN);
    k_wconv<<<(C_HID * C_HID + 255) / 256, 256, 0, stream>>>(W2, Wt2, C_HID);
    k_hist<<<CHK, 256, 0, stream>>>(dst, histT);
    k_hscan<<<1, 1024, 0, stream>>>(histT, histS);
    k_binscat<<<CHK, 256, 0, stream>>>(src, dst, histS, mid);
    k_bcnt<<<NBKT, 256, 0, stream>>>(mid, histS, cnt);
    k_dinv<<<NB, 256, 0, stream>>>(cnt, dinv);
    k_bsum<<<NB, 256, 0, stream>>>(cnt, bsum);
    k_sbs<<<1, 256, 0, stream>>>(bsum, bpre);
    k_write<<<NB, 256, 0, stream>>>(cnt, bpre, rowptr);
    k_binfill<<<NBKT, 256, 0, stream>>>(mid, histS, rowptr, dinv, csr);

    const int gblocks = (NN + 63) / 64;
    const int agblocks = (NN + 7) / 8;
    // layer 1: h1 = x@W1 -> A_bf (bf16) ;  B = h1*dinv^2 (fp32 self-loop init)
    k_gemm_mfma<false, false><<<gblocks, 512, 0, stream>>>(x, Wt1, nullptr, nullptr, dinv, A_bf, B, C_IN);
    // B += gather(h1)
    k_gather<<<agblocks, 256, 0, stream>>>(A_bf, rowptr, csr, B);
    // layer 2: h2 = relu(B + b1)@W2 -> A_bf ; out = h2*dinv^2 + b2 (self-loop init)
    k_gemm_mfma<true, true><<<gblocks, 512, 0, stream>>>(B, Wt2, b1, b2, dinv, A_bf, out, C_HID);
    // out += gather(h2)
    k_gather<<<agblocks, 256, 0, stream>>>(A_bf, rowptr, csr, out);
}

// Round 7
// 300.711 us; speedup vs baseline: 1.1795x; 1.0303x over previous
//
#include <hip/hip_runtime.h>
#include <hip/hip_fp16.h>

#define NN 50000
#define NE 800000
#define C_IN 384
#define C_HID 128
#define NB 196    // ceil(NN/256)
#define CHK 128   // edge chunks
#define ECH 6250  // edges per chunk (128*6250 = 800000)
#define NBKT 128  // dst buckets
#define BSTR 392  // dst stride per bucket (128*392 = 50176 >= NN)

typedef __attribute__((ext_vector_type(8))) short short8;
typedef __attribute__((ext_vector_type(4))) float f32x4;
typedef __attribute__((ext_vector_type(4))) unsigned short us4;

__device__ __forceinline__ ushort f2bf(float x) {
    uint u = __float_as_uint(x);
    uint r = (u + 0x7fffu + ((u >> 16) & 1u)) >> 16;  // RNE
    return (ushort)r;
}
__device__ __forceinline__ float bf2f(ushort b) { return __uint_as_float(((uint)b) << 16); }

typedef __attribute__((address_space(1))) const unsigned int as1_uint;
typedef __attribute__((address_space(3))) unsigned int as3_uint;
__device__ __forceinline__ void gload16(const void* g, void* l) {
    __builtin_amdgcn_global_load_lds((as1_uint*)g, (as3_uint*)l, 16, 0, 0);
}

__global__ __launch_bounds__(256) void k_dinv(const int* __restrict__ cnt,
                                              float* __restrict__ dinv) {
    int i = blockIdx.x * 256 + threadIdx.x;
    if (i < NN) dinv[i] = rsqrtf((float)cnt[i] + 1.0f);  // +1 = self loop
}

// ---------------- hierarchical exclusive scan over NN counts -> rowptr ----------------
__global__ __launch_bounds__(256) void k_bsum(const int* __restrict__ cnt,
                                              int* __restrict__ bsum) {
    __shared__ int part[256];
    const int tid = threadIdx.x;
    const int i = blockIdx.x * 256 + tid;
    part[tid] = (i < NN) ? cnt[i] : 0;
    __syncthreads();
#pragma unroll
    for (int off = 128; off > 0; off >>= 1) {
        if (tid < off) part[tid] += part[tid + off];
        __syncthreads();
    }
    if (tid == 0) bsum[blockIdx.x] = part[0];
}

__global__ __launch_bounds__(256) void k_sbs(const int* __restrict__ bsum,
                                             int* __restrict__ bpre) {
    __shared__ int part[256];
    const int t = threadIdx.x;
    part[t] = (t < NB) ? bsum[t] : 0;
    __syncthreads();
#pragma unroll
    for (int off = 1; off < 256; off <<= 1) {
        int v = (t >= off) ? part[t - off] : 0;
        __syncthreads();
        part[t] += v;
        __syncthreads();
    }
    if (t < NB) bpre[t] = (t == 0) ? 0 : part[t - 1];  // exclusive
}

__global__ __launch_bounds__(256) void k_write(const int* __restrict__ cnt,
                                               const int* __restrict__ bpre,
                                               int* __restrict__ rowptr) {
    __shared__ int part[256];
    const int t = threadIdx.x;
    const int i = blockIdx.x * 256 + t;
    const int v = (i < NN) ? cnt[i] : 0;
    part[t] = v;
    __syncthreads();
#pragma unroll
    for (int off = 1; off < 256; off <<= 1) {
        int u = (t >= off) ? part[t - off] : 0;
        __syncthreads();
        part[t] += u;
        __syncthreads();
    }
    if (i < NN) {
        const int excl = bpre[blockIdx.x] + part[t] - v;
        rowptr[i] = excl;
        if (i == NN - 1) rowptr[NN] = excl + v;
    }
}

// ---------------- bucket pipeline: hist -> hscan -> binscat -> bcnt -> binfill ----------------
__global__ __launch_bounds__(256) void k_hist(const int* __restrict__ dst,
                                              int* __restrict__ histT) {
    __shared__ int h[NBKT];
    const int tid = threadIdx.x;
    if (tid < NBKT) h[tid] = 0;
    __syncthreads();
    const int base = blockIdx.x * ECH;
    for (int i = base + tid; i < base + ECH; i += 256)
        atomicAdd(&h[(uint)dst[i] / BSTR], 1);
    __syncthreads();
    if (tid < NBKT) histT[tid * CHK + blockIdx.x] = h[tid];
}

__global__ __launch_bounds__(1024) void k_hscan(const int* __restrict__ histT,
                                                int* __restrict__ histS) {
    __shared__ int part[1024];
    const int t = threadIdx.x;
    const int base = t * 16;
    int loc[16];
    int s = 0;
#pragma unroll
    for (int i = 0; i < 16; ++i) {
        loc[i] = histT[base + i];
        s += loc[i];
    }
    part[t] = s;
    __syncthreads();
    for (int off = 1; off < 1024; off <<= 1) {
        int v = (t >= off) ? part[t - off] : 0;
        __syncthreads();
        part[t] += v;
        __syncthreads();
    }
    int run = (t == 0) ? 0 : part[t - 1];
#pragma unroll
    for (int i = 0; i < 16; ++i) {
        histS[base + i] = run;
        run += loc[i];
    }
}

// k_binscat: chunks re-read edges, write (dst, src<<16) to bucket-major mid[]
__global__ __launch_bounds__(256) void k_binscat(const int* __restrict__ src,
                                                 const int* __restrict__ dst,
                                                 const int* __restrict__ histS,
                                                 uint2* __restrict__ mid) {
    __shared__ int cur[NBKT];
    const int tid = threadIdx.x;
    if (tid < NBKT) cur[tid] = histS[tid * CHK + blockIdx.x];
    __syncthreads();
    const int base = blockIdx.x * ECH;
    for (int i = base + tid; i < base + ECH; i += 256) {
        const int s = src[i];
        const int d = dst[i];
        const int p = atomicAdd(&cur[(uint)d / BSTR], 1);
        mid[p] = make_uint2((uint)d, (uint)s << 16);
    }
}

// k_bcnt: per-node degree counts from bucketed mid (replaces global atomic k_deg)
__global__ __launch_bounds__(256) void k_bcnt(const uint2* __restrict__ mid,
                                              const int* __restrict__ histS,
                                              int* __restrict__ cnt) {
    __shared__ int cur[BSTR];
    const int tid = threadIdx.x;
    const int b = blockIdx.x;
    for (int j = tid; j < BSTR; j += 256) cur[j] = 0;
    __syncthreads();
    const int lo = histS[b * CHK];
    const int hi = (b < NBKT - 1) ? histS[(b + 1) * CHK] : NE;
    for (int e = lo + tid; e < hi; e += 256)
        atomicAdd(&cur[mid[e].x - (uint)b * BSTR], 1);
    __syncthreads();
    for (int j = tid; j < BSTR; j += 256) {
        const int idx = b * BSTR + j;
        if (idx < NN) cnt[idx] = cur[j];
    }
}

// k_binfill: one block per bucket; computes norm, scatter confined to ~25 KB csr window
__global__ __launch_bounds__(256) void k_binfill(const uint2* __restrict__ mid,
                                                 const int* __restrict__ histS,
                                                 const int* __restrict__ rowptr,
                                                 const float* __restrict__ dinv,
                                                 uint* __restrict__ csr) {
    __shared__ int cur[BSTR];
    __shared__ float sdv[BSTR];
    const int tid = threadIdx.x;
    const int b = blockIdx.x;
    for (int j = tid; j < BSTR; j += 256) {
        const int idx = b * BSTR + j;
        cur[j] = (idx < NN) ? rowptr[idx] : 0;
        sdv[j] = (idx < NN) ? dinv[idx] : 0.f;
    }
    __syncthreads();
    const int lo = histS[b * CHK];
    const int hi = (b < NBKT - 1) ? histS[(b + 1) * CHK] : NE;
    for (int e = lo + tid; e < hi; e += 256) {
        const uint2 u = mid[e];
        const int j = u.x - (uint)b * BSTR;
        const float norm = dinv[u.y >> 16] * sdv[j];
        const int p = atomicAdd(&cur[j], 1);
        csr[p] = u.y | __half_as_ushort(__float2half(norm));
    }
}

// ---------------- W -> fragment-linear hi/lo bf16 split, 32-k blocks ----------------
// per 32-k block: 1024 short8 = 16 KB; hi frags [0,512), lo frags [512,1024)
__global__ __launch_bounds__(256) void k_wconv(const float* __restrict__ W,
                                               ushort* __restrict__ Wt,
                                               int K) {
    int i = blockIdx.x * 256 + threadIdx.x;
    if (i < K * C_HID) {
        int k = i >> 7, n = i & 127;  // N = 128
        float w = W[i];
        ushort h = f2bf(w);
        ushort l = f2bf(w - bf2f(h));
        int blk = k >> 5, kq = (k >> 3) & 3, j = k & 7;
        int t = n >> 4, fr = n & 15, lane = kq * 16 + fr;
        size_t off = ((size_t)blk * 1024 + t * 64 + lane) * 8 + j;
        Wt[off] = h;
        Wt[off + 4096] = l;  // +512 short8
    }
}

// ---------------- split-bf16 MFMA GEMM, BM=64, 8 waves, K_STEP=32 ----------------
// Staging CONVERTS X fp32 -> hi/lo bf16 (once per element); inner loop is pure
// ds_read_b128 + MFMA (no VALU between LDS and MFMA). W via async global_load_lds,
// counted vmcnt(1) at barrier (X prefetch stays in flight across barriers).
#define STAGE_X(NXT, XOLD, KB1)                                                          \
    {                                                                                    \
        float xs0 = XOLD.x, xs1 = XOLD.y, xs2 = XOLD.z, xs3 = XOLD.w;                    \
        if (IN_RELU_BIAS) {                                                              \
            float4 bq = *(const float4*)(&bias_lds[(KB1) * 32 + (tid & 7) * 4]);         \
            xs0 = fmaxf(xs0 + bq.x, 0.f);                                                \
            xs1 = fmaxf(xs1 + bq.y, 0.f);                                                \
            xs2 = fmaxf(xs2 + bq.z, 0.f);                                                \
            xs3 = fmaxf(xs3 + bq.w, 0.f);                                                \
        }                                                                                \
        const uint u0 = __float_as_uint(xs0), u1 = __float_as_uint(xs1);                 \
        const uint u2 = __float_as_uint(xs2), u3 = __float_as_uint(xs3);                 \
        const uint h01 = (u0 >> 16) | (u1 & 0xffff0000u);                                \
        const uint h23 = (u2 >> 16) | (u3 & 0xffff0000u);                                \
        const uint l0 = __float_as_uint(xs0 - __uint_as_float(u0 & 0xffff0000u));        \
        const uint l1 = __float_as_uint(xs1 - __uint_as_float(u1 & 0xffff0000u));        \
        const uint l2 = __float_as_uint(xs2 - __uint_as_float(u2 & 0xffff0000u));        \
        const uint l3 = __float_as_uint(xs3 - __uint_as_float(u3 & 0xffff0000u));        \
        const uint l01 = (l0 >> 16) | (l1 & 0xffff0000u);                                \
        const uint l23 = (l2 >> 16) | (l3 & 0xffff0000u);                                \
        *(uint2*)&XLh[NXT][xw] = make_uint2(h01, h23);                                   \
        *(uint2*)&XLl[NXT][xw] = make_uint2(l01, l23);                                   \
    }

#define GEMM_BODY(KB, CUR, NXT, XOLD, XNEW)                                              \
    {                                                                                    \
        _Pragma("unroll")                                                                \
        for (int i_ = 0; i_ < 2; ++i_)                                                   \
            gload16(Wt8 + (size_t)((KB) + 1) * 1024 + wv * 128 + i_ * 64 + lane,         \
                    &WL[NXT][wv * 128 + i_ * 64]);                                       \
        __builtin_amdgcn_sched_barrier(0);                                               \
        XNEW = *(const float4*)(xsrc + ((KB) + 2) * 32);                                 \
        const short8 ahh = *(const short8*)&XLh[CUR][axh];                               \
        const short8 all = *(const short8*)&XLl[CUR][axh];                               \
        const short8 wh0 = WL[CUR][(tb + 0) * 64 + lane];                                \
        const short8 wl0 = WL[CUR][512 + (tb + 0) * 64 + lane];                          \
        const short8 wh1 = WL[CUR][(tb + 1) * 64 + lane];                                \
        const short8 wl1 = WL[CUR][512 + (tb + 1) * 64 + lane];                          \
        const short8 wh2 = WL[CUR][(tb + 2) * 64 + lane];                                \
        const short8 wl2 = WL[CUR][512 + (tb + 2) * 64 + lane];                          \
        const short8 wh3 = WL[CUR][(tb + 3) * 64 + lane];                                \
        const short8 wl3 = WL[CUR][512 + (tb + 3) * 64 + lane];                          \
        STAGE_X(NXT, XOLD, (KB) + 1);                                                    \
        __builtin_amdgcn_s_setprio(1);                                                   \
        acc[0] = __builtin_amdgcn_mfma_f32_16x16x32_bf16(ahh, wh0, acc[0], 0, 0, 0);     \
        acc[0] = __builtin_amdgcn_mfma_f32_16x16x32_bf16(ahh, wl0, acc[0], 0, 0, 0);     \
        acc[0] = __builtin_amdgcn_mfma_f32_16x16x32_bf16(all, wh0, acc[0], 0, 0, 0);     \
        acc[1] = __builtin_amdgcn_mfma_f32_16x16x32_bf16(ahh, wh1, acc[1], 0, 0, 0);     \
        acc[1] = __builtin_amdgcn_mfma_f32_16x16x32_bf16(ahh, wl1, acc[1], 0, 0, 0);     \
        acc[1] = __builtin_amdgcn_mfma_f32_16x16x32_bf16(all, wh1, acc[1], 0, 0, 0);     \
        acc[2] = __builtin_amdgcn_mfma_f32_16x16x32_bf16(ahh, wh2, acc[2], 0, 0, 0);     \
        acc[2] = __builtin_amdgcn_mfma_f32_16x16x32_bf16(ahh, wl2, acc[2], 0, 0, 0);     \
        acc[2] = __builtin_amdgcn_mfma_f32_16x16x32_bf16(all, wh2, acc[2], 0, 0, 0);     \
        acc[3] = __builtin_amdgcn_mfma_f32_16x16x32_bf16(ahh, wh3, acc[3], 0, 0, 0);     \
        acc[3] = __builtin_amdgcn_mfma_f32_16x16x32_bf16(ahh, wl3, acc[3], 0, 0, 0);     \
        acc[3] = __builtin_amdgcn_mfma_f32_16x16x32_bf16(all, wh3, acc[3], 0, 0, 0);     \
        __builtin_amdgcn_s_setprio(0);                                                   \
        __builtin_amdgcn_sched_barrier(0);                                               \
        asm volatile("s_waitcnt vmcnt(1) lgkmcnt(0)" ::: "memory");                      \
        __builtin_amdgcn_sched_barrier(0);                                               \
        __builtin_amdgcn_s_barrier();                                                    \
    }

// Tail body: no prefetch issue; VM drain count parameterized
#define GEMM_TAIL(KB, CUR, DO_MFMA_ONLY)                                                 \
    {                                                                                    \
        const short8 ahh = *(const short8*)&XLh[CUR][axh];                               \
        const short8 all = *(const short8*)&XLl[CUR][axh];                               \
        const short8 wh0 = WL[CUR][(tb + 0) * 64 + lane];                                \
        const short8 wl0 = WL[CUR][512 + (tb + 0) * 64 + lane];                          \
        const short8 wh1 = WL[CUR][(tb + 1) * 64 + lane];                                \
        const short8 wl1 = WL[CUR][512 + (tb + 1) * 64 + lane];                          \
        const short8 wh2 = WL[CUR][(tb + 2) * 64 + lane];                                \
        const short8 wl2 = WL[CUR][512 + (tb + 2) * 64 + lane];                          \
        const short8 wh3 = WL[CUR][(tb + 3) * 64 + lane];                                \
        const short8 wl3 = WL[CUR][512 + (tb + 3) * 64 + lane];                          \
        acc[0] = __builtin_amdgcn_mfma_f32_16x16x32_bf16(ahh, wh0, acc[0], 0, 0, 0);     \
        acc[0] = __builtin_amdgcn_mfma_f32_16x16x32_bf16(ahh, wl0, acc[0], 0, 0, 0);     \
        acc[0] = __builtin_amdgcn_mfma_f32_16x16x32_bf16(all, wh0, acc[0], 0, 0, 0);     \
        acc[1] = __builtin_amdgcn_mfma_f32_16x16x32_bf16(ahh, wh1, acc[1], 0, 0, 0);     \
        acc[1] = __builtin_amdgcn_mfma_f32_16x16x32_bf16(ahh, wl1, acc[1], 0, 0, 0);     \
        acc[1] = __builtin_amdgcn_mfma_f32_16x16x32_bf16(all, wh1, acc[1], 0, 0, 0);     \
        acc[2] = __builtin_amdgcn_mfma_f32_16x16x32_bf16(ahh, wh2, acc[2], 0, 0, 0);     \
        acc[2] = __builtin_amdgcn_mfma_f32_16x16x32_bf16(ahh, wl2, acc[2], 0, 0, 0);     \
        acc[2] = __builtin_amdgcn_mfma_f32_16x16x32_bf16(all, wh2, acc[2], 0, 0, 0);     \
        acc[3] = __builtin_amdgcn_mfma_f32_16x16x32_bf16(ahh, wh3, acc[3], 0, 0, 0);     \
        acc[3] = __builtin_amdgcn_mfma_f32_16x16x32_bf16(ahh, wl3, acc[3], 0, 0, 0);     \
        acc[3] = __builtin_amdgcn_mfma_f32_16x16x32_bf16(all, wh3, acc[3], 0, 0, 0);     \
    }

template <bool IN_RELU_BIAS, bool OUT_BIAS>
__global__ __launch_bounds__(512) void k_gemm_mfma(const float* __restrict__ X,
                                                   const ushort* __restrict__ Wt,
                                                   const float* __restrict__ bin,
                                                   const float* __restrict__ bout,
                                                   const float* __restrict__ dinv,
                                                   ushort* __restrict__ out_main,
                                                   float* __restrict__ out_self,
                                                   int K) {
    __shared__ short8 WL[2][1024];    // 2 x 16 KB W double buffer (frag-linear hi+lo)
    __shared__ ushort XLh[2][2048];   // 2 x 4 KB X hi (64 rows x 32 k, swizzled)
    __shared__ ushort XLl[2][2048];   // 2 x 4 KB X lo
    __shared__ float bias_lds[128];

    const int tid = threadIdx.x;
    const int bm = blockIdx.x * 64;
    const int wv = tid >> 6;
    const int lane = tid & 63;
    const int fr = lane & 15;
    const int kq = lane >> 4;
    const int g = wv >> 1;   // 0..3 row-group
    const int ch = wv & 1;   // col half
    const int tb = ch * 4;   // first col tile
    const int NK = K >> 5;   // 12 (K=384) or 4 (K=128) -- always even, >= 4

    const short8* Wt8 = (const short8*)Wt;

    // X staging: thread loads one float4 (4 k-elems), row-contiguous (coalesced)
    const int xr = tid >> 3;   // 0..63 row in tile
    const int xc8 = tid & 7;   // 8B half-chunk index (4 elems)
    int xrow = bm + xr;
    if (xrow >= NN) xrow = NN - 1;
    const float* xsrc = X + (size_t)xrow * K + xc8 * 4;
    // write idx (ushort units): 16B chunk = (xc8>>1)^(row&3), half = xc8&1
    const int xw = xr * 32 + (((xc8 >> 1) ^ (xr & 3)) << 3) + ((xc8 & 1) << 2);

    // A-frag read idx: row ar, 16B chunk kq^(ar&3)
    const int ar = g * 16 + fr;
    const int axh = ar * 32 + ((kq ^ (ar & 3)) << 3);

    f32x4 acc[4];
#pragma unroll
    for (int t = 0; t < 4; ++t) acc[t] = (f32x4){0.f, 0.f, 0.f, 0.f};

    if (IN_RELU_BIAS && tid < 128) bias_lds[tid] = bin[tid];

    // ---- prologue ----
#pragma unroll
    for (int i_ = 0; i_ < 2; ++i_)
        gload16(Wt8 + (size_t)wv * 128 + i_ * 64 + lane, &WL[0][wv * 128 + i_ * 64]);
    __builtin_amdgcn_sched_barrier(0);
    float4 xA = *(const float4*)(xsrc);        // X(0)
    float4 xB = *(const float4*)(xsrc + 32);   // X(1)
    // bias visibility barrier (no vmcnt drain; loads stay in flight)
    asm volatile("s_waitcnt lgkmcnt(0)" ::: "memory");
    __builtin_amdgcn_s_barrier();
    STAGE_X(0, xA, 0);                         // waits xA (drains W gloads too), converts
    xA = xB;                                   // xA now holds X(1) entering iter 0
    asm volatile("s_waitcnt lgkmcnt(0)" ::: "memory");
    __builtin_amdgcn_s_barrier();

    // ---- main loop: bodies KB = 0 .. NK-3 ----
    for (int kb = 0; kb < NK - 2; kb += 2) {
        GEMM_BODY(kb, 0, 1, xA, xB);
        GEMM_BODY(kb + 1, 1, 0, xB, xA);
    }

    // ---- tail KB = NK-2 (CUR=0): last gloads + last stage, full drain ----
    {
        const int KB = NK - 2;
#pragma unroll
        for (int i_ = 0; i_ < 2; ++i_)
            gload16(Wt8 + (size_t)(KB + 1) * 1024 + wv * 128 + i_ * 64 + lane,
                    &WL[1][wv * 128 + i_ * 64]);
        STAGE_X(1, xA, KB + 1);  // stage X(NK-1)
        GEMM_TAIL(KB, 0, 0);
        __builtin_amdgcn_sched_barrier(0);
        asm volatile("s_waitcnt vmcnt(0) lgkmcnt(0)" ::: "memory");
        __builtin_amdgcn_sched_barrier(0);
        __builtin_amdgcn_s_barrier();
    }
    // ---- tail KB = NK-1 (CUR=1): compute only ----
    GEMM_TAIL(NK - 1, 1, 1);

    // ---- epilogue: D(lane,reg): m = bm + g*16 + kq*4 + r, n = (ch*4+t)*16 + fr ----
#pragma unroll
    for (int r = 0; r < 4; ++r) {
        const int m = bm + g * 16 + kq * 4 + r;
        if (m < NN) {
            const float dv = dinv[m];
            const float d2 = dv * dv;
            ushort* om = out_main + (size_t)m * C_HID;
            float* os = out_self + (size_t)m * C_HID;
#pragma unroll
            for (int t = 0; t < 4; ++t) {
                const int n = (ch * 4 + t) * 16 + fr;
                const float v = acc[t][r];
                om[n] = f2bf(v);
                os[n] = v * d2 + (OUT_BIAS ? bout[n] : 0.f);
            }
        }
    }
}

// ---------------- CSR gather: out[d] = init(out[d]) + sum_e bf16(h[src_e])*norm_e ----------------
__global__ __launch_bounds__(256) void k_gather(const ushort* __restrict__ h,
                                                const int* __restrict__ rowptr,
                                                const uint* __restrict__ csr,
                                                float* __restrict__ out) {
    const int tid = threadIdx.x;
    const int node = blockIdx.x * 8 + (tid >> 5);
    if (node >= NN) return;
    const int lane = tid & 31;
    const int c = lane * 4;
    const int beg = rowptr[node];
    const int end = rowptr[node + 1];

    float4 acc = *(const float4*)(out + (size_t)node * C_HID + c);  // self-loop init

    for (int j0 = beg; j0 < end; j0 += 32) {
        const int n = end - j0;
        uint myE = 0;
        if (lane < n) myE = csr[j0 + lane];
        const int m = n < 32 ? n : 32;
        int jj = 0;
        for (; jj + 4 <= m; jj += 4) {
            const uint e0 = (uint)__shfl((int)myE, jj + 0, 32);
            const uint e1 = (uint)__shfl((int)myE, jj + 1, 32);
            const uint e2 = (uint)__shfl((int)myE, jj + 2, 32);
            const uint e3 = (uint)__shfl((int)myE, jj + 3, 32);
            const us4 u0 = *(const us4*)(h + (size_t)(e0 >> 16) * C_HID + c);
            const us4 u1 = *(const us4*)(h + (size_t)(e1 >> 16) * C_HID + c);
            const us4 u2 = *(const us4*)(h + (size_t)(e2 >> 16) * C_HID + c);
            const us4 u3 = *(const us4*)(h + (size_t)(e3 >> 16) * C_HID + c);
            const float n0 = __half2float(__ushort_as_half((ushort)(e0 & 0xffffu)));
            const float n1 = __half2float(__ushort_as_half((ushort)(e1 & 0xffffu)));
            const float n2 = __half2float(__ushort_as_half((ushort)(e2 & 0xffffu)));
            const float n3 = __half2float(__ushort_as_half((ushort)(e3 & 0xffffu)));
            acc.x = fmaf(bf2f(u0[0]), n0, acc.x);
            acc.y = fmaf(bf2f(u0[1]), n0, acc.y);
            acc.z = fmaf(bf2f(u0[2]), n0, acc.z);
            acc.w = fmaf(bf2f(u0[3]), n0, acc.w);
            acc.x = fmaf(bf2f(u1[0]), n1, acc.x);
            acc.y = fmaf(bf2f(u1[1]), n1, acc.y);
            acc.z = fmaf(bf2f(u1[2]), n1, acc.z);
            acc.w = fmaf(bf2f(u1[3]), n1, acc.w);
            acc.x = fmaf(bf2f(u2[0]), n2, acc.x);
            acc.y = fmaf(bf2f(u2[1]), n2, acc.y);
            acc.z = fmaf(bf2f(u2[2]), n2, acc.z);
            acc.w = fmaf(bf2f(u2[3]), n2, acc.w);
            acc.x = fmaf(bf2f(u3[0]), n3, acc.x);
            acc.y = fmaf(bf2f(u3[1]), n3, acc.y);
            acc.z = fmaf(bf2f(u3[2]), n3, acc.z);
            acc.w = fmaf(bf2f(u3[3]), n3, acc.w);
        }
        for (; jj < m; ++jj) {
            const uint ev = (uint)__shfl((int)myE, jj, 32);
            const us4 u = *(const us4*)(h + (size_t)(ev >> 16) * C_HID + c);
            const float nw = __half2float(__ushort_as_half((ushort)(ev & 0xffffu)));
            acc.x = fmaf(bf2f(u[0]), nw, acc.x);
            acc.y = fmaf(bf2f(u[1]), nw, acc.y);
            acc.z = fmaf(bf2f(u[2]), nw, acc.z);
            acc.w = fmaf(bf2f(u[3]), nw, acc.w);
        }
    }
    *(float4*)(out + (size_t)node * C_HID + c) = acc;
}

extern "C" void kernel_launch(void* const* d_in, const int* in_sizes, int n_in,
                              void* d_out, int out_size, void* d_ws, size_t ws_size,
                              hipStream_t stream) {
    const float* x = (const float*)d_in[0];
    const int* ei = (const int*)d_in[1];
    const float* W1 = (const float*)d_in[2];
    const float* b1 = (const float*)d_in[3];
    const float* W2 = (const float*)d_in[4];
    const float* b2 = (const float*)d_in[5];
    float* out = (float*)d_out;

    const int* src = ei;
    const int* dst = ei + NE;

    // workspace layout (4-byte units)
    int* cnt = (int*)d_ws;                       // 50048
    int* rowptr = cnt + 50048;                   // 50064 (NN+1)
    float* dinv = (float*)(rowptr + 50064);      // 50048
    int* bsum = (int*)(dinv + 50048);            // 256
    int* bpre = bsum + 256;                      // 256
    int* histT = bpre + 256;                     // 16384
    int* histS = histT + 16384;                  // 16384
    ushort* Wt1 = (ushort*)(histS + 16384);      // 98304 shorts (frag-linear hi+lo)
    ushort* Wt2 = Wt1 + 98304;                   // 32768 shorts
    uint* csr = (uint*)(Wt2 + 32768);            // NE uints
    uint2* mid = (uint2*)(csr + NE);             // NE uint2
    ushort* A_bf = (ushort*)(mid + NE);          // NN*128 shorts (h bf16)
    float* B = (float*)(A_bf + (size_t)NN * C_HID);  // NN*128 fp32 (agg buffer)

    k_wconv<<<(C_IN * C_HID + 255) / 256, 256, 0, stream>>>(W1, Wt1, C_IN);
    k_wconv<<<(C_HID * C_HID + 255) / 256, 256, 0, stream>>>(W2, Wt2, C_HID);
    k_hist<<<CHK, 256, 0, stream>>>(dst, histT);
    k_hscan<<<1, 1024, 0, stream>>>(histT, histS);
    k_binscat<<<CHK, 256, 0, stream>>>(src, dst, histS, mid);
    k_bcnt<<<NBKT, 256, 0, stream>>>(mid, histS, cnt);
    k_dinv<<<NB, 256, 0, stream>>>(cnt, dinv);
    k_bsum<<<NB, 256, 0, stream>>>(cnt, bsum);
    k_sbs<<<1, 256, 0, stream>>>(bsum, bpre);
    k_write<<<NB, 256, 0, stream>>>(cnt, bpre, rowptr);
    k_binfill<<<NBKT, 256, 0, stream>>>(mid, histS, rowptr, dinv, csr);

    const int gblocks = (NN + 63) / 64;
    const int agblocks = (NN + 7) / 8;
    // layer 1: h1 = x@W1 -> A_bf (bf16) ;  B = h1*dinv^2 (fp32 self-loop init)
    k_gemm_mfma<false, false><<<gblocks, 512, 0, stream>>>(x, Wt1, nullptr, nullptr, dinv, A_bf, B, C_IN);
    // B += gather(h1)
    k_gather<<<agblocks, 256, 0, stream>>>(A_bf, rowptr, csr, B);
    // layer 2: h2 = relu(B + b1)@W2 -> A_bf ; out = h2*dinv^2 + b2 (self-loop init)
    k_gemm_mfma<true, true><<<gblocks, 512, 0, stream>>>(B, Wt2, b1, b2, dinv, A_bf, out, C_HID);
    // out += gather(h2)
    k_gather<<<agblocks, 256, 0, stream>>>(A_bf, rowptr, csr, out);
}

// Round 9
// 296.903 us; speedup vs baseline: 1.1946x; 1.0128x over previous
//
#include <hip/hip_runtime.h>
#include <hip/hip_fp16.h>

#define NN 50000
#define NE 800000
#define C_IN 384
#define C_HID 128
#define CHK 128   // edge chunks
#define ECH 6250  // edges per chunk (128*6250 = 800000)
#define NBKT 128  // dst buckets
#define BSTR 392  // dst stride per bucket (128*392 = 50176 >= NN)

typedef __attribute__((ext_vector_type(8))) short short8;
typedef __attribute__((ext_vector_type(4))) float f32x4;
typedef __attribute__((ext_vector_type(8))) unsigned short us8;

__device__ __forceinline__ ushort f2bf(float x) {
    uint u = __float_as_uint(x);
    uint r = (u + 0x7fffu + ((u >> 16) & 1u)) >> 16;  // RNE
    return (ushort)r;
}
__device__ __forceinline__ float bf2f(ushort b) { return __uint_as_float(((uint)b) << 16); }

typedef __attribute__((address_space(1))) const unsigned int as1_uint;
typedef __attribute__((address_space(3))) unsigned int as3_uint;
__device__ __forceinline__ void gload16(const void* g, void* l) {
    __builtin_amdgcn_global_load_lds((as1_uint*)g, (as3_uint*)l, 16, 0, 0);
}

// ---------------- bucket pipeline: hist -> hscan -> binscat -> bcnt_scan -> binfill --------
__global__ __launch_bounds__(256) void k_hist(const int* __restrict__ dst,
                                              int* __restrict__ histT) {
    __shared__ int h[NBKT];
    const int tid = threadIdx.x;
    if (tid < NBKT) h[tid] = 0;
    __syncthreads();
    const int base = blockIdx.x * ECH;
    for (int i = base + tid; i < base + ECH; i += 256)
        atomicAdd(&h[(uint)dst[i] / BSTR], 1);
    __syncthreads();
    if (tid < NBKT) histT[tid * CHK + blockIdx.x] = h[tid];
}

__global__ __launch_bounds__(1024) void k_hscan(const int* __restrict__ histT,
                                                int* __restrict__ histS) {
    __shared__ int part[1024];
    const int t = threadIdx.x;
    const int base = t * 16;
    int loc[16];
    int s = 0;
#pragma unroll
    for (int i = 0; i < 16; ++i) {
        loc[i] = histT[base + i];
        s += loc[i];
    }
    part[t] = s;
    __syncthreads();
    for (int off = 1; off < 1024; off <<= 1) {
        int v = (t >= off) ? part[t - off] : 0;
        __syncthreads();
        part[t] += v;
        __syncthreads();
    }
    int run = (t == 0) ? 0 : part[t - 1];
#pragma unroll
    for (int i = 0; i < 16; ++i) {
        histS[base + i] = run;
        run += loc[i];
    }
}

// k_binscat: chunks re-read edges, write (dst, src<<16) to bucket-major mid[]
__global__ __launch_bounds__(256) void k_binscat(const int* __restrict__ src,
                                                 const int* __restrict__ dst,
                                                 const int* __restrict__ histS,
                                                 uint2* __restrict__ mid) {
    __shared__ int cur[NBKT];
    const int tid = threadIdx.x;
    if (tid < NBKT) cur[tid] = histS[tid * CHK + blockIdx.x];
    __syncthreads();
    const int base = blockIdx.x * ECH;
    for (int i = base + tid; i < base + ECH; i += 256) {
        const int s = src[i];
        const int d = dst[i];
        const int p = atomicAdd(&cur[(uint)d / BSTR], 1);
        mid[p] = make_uint2((uint)d, (uint)s << 16);
    }
}

// k_bcnt_scan: per-node counts + within-bucket exclusive scan -> rowptr + dinv.
// bucket base histS[b*CHK] IS the global prefix at the bucket start, so rowptr is
// bit-identical to a global scan.
// FIX (R8 bug): writes MUST be guarded by i0 < BSTR -- the 512-slot scan range
// exceeds the bucket's 392 nodes, and unguarded writes landed in the NEXT bucket's
// node range (cross-block race: rowptr=lo, dinv=1.0 clobbered ~119 nodes/bucket).
__global__ __launch_bounds__(256) void k_bcnt_scan(const uint2* __restrict__ mid,
                                                   const int* __restrict__ histS,
                                                   int* __restrict__ rowptr,
                                                   float* __restrict__ dinv) {
    __shared__ int cur[BSTR];
    __shared__ int part[256];
    const int tid = threadIdx.x;
    const int b = blockIdx.x;
    for (int j = tid; j < BSTR; j += 256) cur[j] = 0;
    __syncthreads();
    const int lo = histS[b * CHK];
    const int hi = (b < NBKT - 1) ? histS[(b + 1) * CHK] : NE;
    for (int e = lo + tid; e < hi; e += 256)
        atomicAdd(&cur[mid[e].x - (uint)b * BSTR], 1);
    __syncthreads();
    // scan: thread t owns elems 2t, 2t+1 (BSTR=392 <= 512)
    const int i0 = 2 * tid;
    const int v0 = (i0 < BSTR) ? cur[i0] : 0;
    const int v1 = (i0 + 1 < BSTR) ? cur[i0 + 1] : 0;
    part[tid] = v0 + v1;
    __syncthreads();
    for (int off = 1; off < 256; off <<= 1) {
        int v = (tid >= off) ? part[tid - off] : 0;
        __syncthreads();
        part[tid] += v;
        __syncthreads();
    }
    const int base = lo + ((tid > 0) ? part[tid - 1] : 0);
    const int idx0 = b * BSTR + i0;
    if (i0 < BSTR && idx0 < NN) {
        rowptr[idx0] = base;
        dinv[idx0] = rsqrtf((float)v0 + 1.0f);  // +1 = self loop
    }
    if (i0 + 1 < BSTR && idx0 + 1 < NN) {
        rowptr[idx0 + 1] = base + v0;
        dinv[idx0 + 1] = rsqrtf((float)v1 + 1.0f);
    }
    if (b == NBKT - 1 && tid == 0) rowptr[NN] = NE;
}

// k_binfill: one block per bucket; computes norm, scatter confined to ~25 KB csr window
__global__ __launch_bounds__(256) void k_binfill(const uint2* __restrict__ mid,
                                                 const int* __restrict__ histS,
                                                 const int* __restrict__ rowptr,
                                                 const float* __restrict__ dinv,
                                                 uint* __restrict__ csr) {
    __shared__ int cur[BSTR];
    __shared__ float sdv[BSTR];
    const int tid = threadIdx.x;
    const int b = blockIdx.x;
    for (int j = tid; j < BSTR; j += 256) {
        const int idx = b * BSTR + j;
        cur[j] = (idx < NN) ? rowptr[idx] : 0;
        sdv[j] = (idx < NN) ? dinv[idx] : 0.f;
    }
    __syncthreads();
    const int lo = histS[b * CHK];
    const int hi = (b < NBKT - 1) ? histS[(b + 1) * CHK] : NE;
    for (int e = lo + tid; e < hi; e += 256) {
        const uint2 u = mid[e];
        const int j = u.x - (uint)b * BSTR;
        const float norm = dinv[u.y >> 16] * sdv[j];
        const int p = atomicAdd(&cur[j], 1);
        csr[p] = u.y | __half_as_ushort(__float2half(norm));
    }
}

// ---------------- W1+W2 -> fragment-linear hi/lo bf16 split, one launch ----------------
// per 32-k block: 1024 short8 = 16 KB; hi frags [0,512), lo frags [512,1024)
__device__ __forceinline__ void wconv_one(const float* W, ushort* Wt, int i) {
    int k = i >> 7, n = i & 127;  // N = 128
    float w = W[i];
    ushort h = f2bf(w);
    ushort l = f2bf(w - bf2f(h));
    int blk = k >> 5, kq = (k >> 3) & 3, j = k & 7;
    int t = n >> 4, fr = n & 15, lane = kq * 16 + fr;
    size_t off = ((size_t)blk * 1024 + t * 64 + lane) * 8 + j;
    Wt[off] = h;
    Wt[off + 4096] = l;  // +512 short8
}

__global__ __launch_bounds__(256) void k_wconv2(const float* __restrict__ W1,
                                                const float* __restrict__ W2,
                                                ushort* __restrict__ Wt1,
                                                ushort* __restrict__ Wt2) {
    int i = blockIdx.x * 256 + threadIdx.x;
    if (i < C_IN * C_HID) {
        wconv_one(W1, Wt1, i);
    } else {
        int j = i - C_IN * C_HID;
        if (j < C_HID * C_HID) wconv_one(W2, Wt2, j);
    }
}

// ---------------- split-bf16 MFMA GEMM, BM=64, 8 waves, K_STEP=32 (unchanged) ----
#define STAGE_X(NXT, XOLD, KB1)                                                          \
    {                                                                                    \
        float xs0 = XOLD.x, xs1 = XOLD.y, xs2 = XOLD.z, xs3 = XOLD.w;                    \
        if (IN_RELU_BIAS) {                                                              \
            float4 bq = *(const float4*)(&bias_lds[(KB1) * 32 + (tid & 7) * 4]);         \
            xs0 = fmaxf(xs0 + bq.x, 0.f);                                                \
            xs1 = fmaxf(xs1 + bq.y, 0.f);                                                \
            xs2 = fmaxf(xs2 + bq.z, 0.f);                                                \
            xs3 = fmaxf(xs3 + bq.w, 0.f);                                                \
        }                                                                                \
        const uint u0 = __float_as_uint(xs0), u1 = __float_as_uint(xs1);                 \
        const uint u2 = __float_as_uint(xs2), u3 = __float_as_uint(xs3);                 \
        const uint h01 = (u0 >> 16) | (u1 & 0xffff0000u);                                \
        const uint h23 = (u2 >> 16) | (u3 & 0xffff0000u);                                \
        const uint l0 = __float_as_uint(xs0 - __uint_as_float(u0 & 0xffff0000u));        \
        const uint l1 = __float_as_uint(xs1 - __uint_as_float(u1 & 0xffff0000u));        \
        const uint l2 = __float_as_uint(xs2 - __uint_as_float(u2 & 0xffff0000u));        \
        const uint l3 = __float_as_uint(xs3 - __uint_as_float(u3 & 0xffff0000u));        \
        const uint l01 = (l0 >> 16) | (l1 & 0xffff0000u);                                \
        const uint l23 = (l2 >> 16) | (l3 & 0xffff0000u);                                \
        *(uint2*)&XLh[NXT][xw] = make_uint2(h01, h23);                                   \
        *(uint2*)&XLl[NXT][xw] = make_uint2(l01, l23);                                   \
    }

#define GEMM_BODY(KB, CUR, NXT, XOLD, XNEW)                                              \
    {                                                                                    \
        _Pragma("unroll")                                                                \
        for (int i_ = 0; i_ < 2; ++i_)                                                   \
            gload16(Wt8 + (size_t)((KB) + 1) * 1024 + wv * 128 + i_ * 64 + lane,         \
                    &WL[NXT][wv * 128 + i_ * 64]);                                       \
        __builtin_amdgcn_sched_barrier(0);                                               \
        XNEW = *(const float4*)(xsrc + ((KB) + 2) * 32);                                 \
        const short8 ahh = *(const short8*)&XLh[CUR][axh];                               \
        const short8 all = *(const short8*)&XLl[CUR][axh];                               \
        const short8 wh0 = WL[CUR][(tb + 0) * 64 + lane];                                \
        const short8 wl0 = WL[CUR][512 + (tb + 0) * 64 + lane];                          \
        const short8 wh1 = WL[CUR][(tb + 1) * 64 + lane];                                \
        const short8 wl1 = WL[CUR][512 + (tb + 1) * 64 + lane];                          \
        const short8 wh2 = WL[CUR][(tb + 2) * 64 + lane];                                \
        const short8 wl2 = WL[CUR][512 + (tb + 2) * 64 + lane];                          \
        const short8 wh3 = WL[CUR][(tb + 3) * 64 + lane];                                \
        const short8 wl3 = WL[CUR][512 + (tb + 3) * 64 + lane];                          \
        STAGE_X(NXT, XOLD, (KB) + 1);                                                    \
        __builtin_amdgcn_s_setprio(1);                                                   \
        acc[0] = __builtin_amdgcn_mfma_f32_16x16x32_bf16(ahh, wh0, acc[0], 0, 0, 0);     \
        acc[0] = __builtin_amdgcn_mfma_f32_16x16x32_bf16(ahh, wl0, acc[0], 0, 0, 0);     \
        acc[0] = __builtin_amdgcn_mfma_f32_16x16x32_bf16(all, wh0, acc[0], 0, 0, 0);     \
        acc[1] = __builtin_amdgcn_mfma_f32_16x16x32_bf16(ahh, wh1, acc[1], 0, 0, 0);     \
        acc[1] = __builtin_amdgcn_mfma_f32_16x16x32_bf16(ahh, wl1, acc[1], 0, 0, 0);     \
        acc[1] = __builtin_amdgcn_mfma_f32_16x16x32_bf16(all, wh1, acc[1], 0, 0, 0);     \
        acc[2] = __builtin_amdgcn_mfma_f32_16x16x32_bf16(ahh, wh2, acc[2], 0, 0, 0);     \
        acc[2] = __builtin_amdgcn_mfma_f32_16x16x32_bf16(ahh, wl2, acc[2], 0, 0, 0);     \
        acc[2] = __builtin_amdgcn_mfma_f32_16x16x32_bf16(all, wh2, acc[2], 0, 0, 0);     \
        acc[3] = __builtin_amdgcn_mfma_f32_16x16x32_bf16(ahh, wh3, acc[3], 0, 0, 0);     \
        acc[3] = __builtin_amdgcn_mfma_f32_16x16x32_bf16(ahh, wl3, acc[3], 0, 0, 0);     \
        acc[3] = __builtin_amdgcn_mfma_f32_16x16x32_bf16(all, wh3, acc[3], 0, 0, 0);     \
        __builtin_amdgcn_s_setprio(0);                                                   \
        __builtin_amdgcn_sched_barrier(0);                                               \
        asm volatile("s_waitcnt vmcnt(1) lgkmcnt(0)" ::: "memory");                      \
        __builtin_amdgcn_sched_barrier(0);                                               \
        __builtin_amdgcn_s_barrier();                                                    \
    }

#define GEMM_TAIL(CUR)                                                                   \
    {                                                                                    \
        const short8 ahh = *(const short8*)&XLh[CUR][axh];                               \
        const short8 all = *(const short8*)&XLl[CUR][axh];                               \
        const short8 wh0 = WL[CUR][(tb + 0) * 64 + lane];                                \
        const short8 wl0 = WL[CUR][512 + (tb + 0) * 64 + lane];                          \
        const short8 wh1 = WL[CUR][(tb + 1) * 64 + lane];                                \
        const short8 wl1 = WL[CUR][512 + (tb + 1) * 64 + lane];                          \
        const short8 wh2 = WL[CUR][(tb + 2) * 64 + lane];                                \
        const short8 wl2 = WL[CUR][512 + (tb + 2) * 64 + lane];                          \
        const short8 wh3 = WL[CUR][(tb + 3) * 64 + lane];                                \
        const short8 wl3 = WL[CUR][512 + (tb + 3) * 64 + lane];                          \
        acc[0] = __builtin_amdgcn_mfma_f32_16x16x32_bf16(ahh, wh0, acc[0], 0, 0, 0);     \
        acc[0] = __builtin_amdgcn_mfma_f32_16x16x32_bf16(ahh, wl0, acc[0], 0, 0, 0);     \
        acc[0] = __builtin_amdgcn_mfma_f32_16x16x32_bf16(all, wh0, acc[0], 0, 0, 0);     \
        acc[1] = __builtin_amdgcn_mfma_f32_16x16x32_bf16(ahh, wh1, acc[1], 0, 0, 0);     \
        acc[1] = __builtin_amdgcn_mfma_f32_16x16x32_bf16(ahh, wl1, acc[1], 0, 0, 0);     \
        acc[1] = __builtin_amdgcn_mfma_f32_16x16x32_bf16(all, wh1, acc[1], 0, 0, 0);     \
        acc[2] = __builtin_amdgcn_mfma_f32_16x16x32_bf16(ahh, wh2, acc[2], 0, 0, 0);     \
        acc[2] = __builtin_amdgcn_mfma_f32_16x16x32_bf16(ahh, wl2, acc[2], 0, 0, 0);     \
        acc[2] = __builtin_amdgcn_mfma_f32_16x16x32_bf16(all, wh2, acc[2], 0, 0, 0);     \
        acc[3] = __builtin_amdgcn_mfma_f32_16x16x32_bf16(ahh, wh3, acc[3], 0, 0, 0);     \
        acc[3] = __builtin_amdgcn_mfma_f32_16x16x32_bf16(ahh, wl3, acc[3], 0, 0, 0);     \
        acc[3] = __builtin_amdgcn_mfma_f32_16x16x32_bf16(all, wh3, acc[3], 0, 0, 0);     \
    }

template <bool IN_RELU_BIAS, bool OUT_BIAS>
__global__ __launch_bounds__(512) void k_gemm_mfma(const float* __restrict__ X,
                                                   const ushort* __restrict__ Wt,
                                                   const float* __restrict__ bin,
                                                   const float* __restrict__ bout,
                                                   const float* __restrict__ dinv,
                                                   ushort* __restrict__ out_main,
                                                   float* __restrict__ out_self,
                                                   int K) {
    __shared__ short8 WL[2][1024];    // 2 x 16 KB W double buffer (frag-linear hi+lo)
    __shared__ ushort XLh[2][2048];   // 2 x 4 KB X hi (64 rows x 32 k, swizzled)
    __shared__ ushort XLl[2][2048];   // 2 x 4 KB X lo
    __shared__ float bias_lds[128];

    const int tid = threadIdx.x;
    const int bm = blockIdx.x * 64;
    const int wv = tid >> 6;
    const int lane = tid & 63;
    const int fr = lane & 15;
    const int kq = lane >> 4;
    const int g = wv >> 1;   // 0..3 row-group
    const int ch = wv & 1;   // col half
    const int tb = ch * 4;   // first col tile
    const int NK = K >> 5;   // 12 (K=384) or 4 (K=128) -- always even, >= 4

    const short8* Wt8 = (const short8*)Wt;

    // X staging: thread loads one float4 (4 k-elems), row-contiguous (coalesced)
    const int xr = tid >> 3;   // 0..63 row in tile
    const int xc8 = tid & 7;   // 8B half-chunk index (4 elems)
    int xrow = bm + xr;
    if (xrow >= NN) xrow = NN - 1;
    const float* xsrc = X + (size_t)xrow * K + xc8 * 4;
    // write idx (ushort units): 16B chunk = (xc8>>1)^(row&3), half = xc8&1
    const int xw = xr * 32 + (((xc8 >> 1) ^ (xr & 3)) << 3) + ((xc8 & 1) << 2);

    // A-frag read idx: row ar, 16B chunk kq^(ar&3)
    const int ar = g * 16 + fr;
    const int axh = ar * 32 + ((kq ^ (ar & 3)) << 3);

    f32x4 acc[4];
#pragma unroll
    for (int t = 0; t < 4; ++t) acc[t] = (f32x4){0.f, 0.f, 0.f, 0.f};

    if (IN_RELU_BIAS && tid < 128) bias_lds[tid] = bin[tid];

    // ---- prologue ----
#pragma unroll
    for (int i_ = 0; i_ < 2; ++i_)
        gload16(Wt8 + (size_t)wv * 128 + i_ * 64 + lane, &WL[0][wv * 128 + i_ * 64]);
    __builtin_amdgcn_sched_barrier(0);
    float4 xA = *(const float4*)(xsrc);        // X(0)
    float4 xB = *(const float4*)(xsrc + 32);   // X(1)
    // bias visibility barrier (no vmcnt drain; loads stay in flight)
    asm volatile("s_waitcnt lgkmcnt(0)" ::: "memory");
    __builtin_amdgcn_s_barrier();
    STAGE_X(0, xA, 0);                         // waits xA (drains W gloads too), converts
    xA = xB;                                   // xA now holds X(1) entering iter 0
    asm volatile("s_waitcnt lgkmcnt(0)" ::: "memory");
    __builtin_amdgcn_s_barrier();

    // ---- main loop: bodies KB = 0 .. NK-3 ----
    for (int kb = 0; kb < NK - 2; kb += 2) {
        GEMM_BODY(kb, 0, 1, xA, xB);
        GEMM_BODY(kb + 1, 1, 0, xB, xA);
    }

    // ---- tail KB = NK-2 (CUR=0): last gloads + last stage, full drain ----
    {
        const int KB = NK - 2;
#pragma unroll
        for (int i_ = 0; i_ < 2; ++i_)
            gload16(Wt8 + (size_t)(KB + 1) * 1024 + wv * 128 + i_ * 64 + lane,
                    &WL[1][wv * 128 + i_ * 64]);
        STAGE_X(1, xA, KB + 1);  // stage X(NK-1)
        GEMM_TAIL(0);
        __builtin_amdgcn_sched_barrier(0);
        asm volatile("s_waitcnt vmcnt(0) lgkmcnt(0)" ::: "memory");
        __builtin_amdgcn_sched_barrier(0);
        __builtin_amdgcn_s_barrier();
    }
    // ---- tail KB = NK-1 (CUR=1): compute only ----
    GEMM_TAIL(1);

    // ---- epilogue: D(lane,reg): m = bm + g*16 + kq*4 + r, n = (ch*4+t)*16 + fr ----
#pragma unroll
    for (int r = 0; r < 4; ++r) {
        const int m = bm + g * 16 + kq * 4 + r;
        if (m < NN) {
            const float dv = dinv[m];
            const float d2 = dv * dv;
            ushort* om = out_main + (size_t)m * C_HID;
            float* os = out_self + (size_t)m * C_HID;
#pragma unroll
            for (int t = 0; t < 4; ++t) {
                const int n = (ch * 4 + t) * 16 + fr;
                const float v = acc[t][r];
                om[n] = f2bf(v);
                os[n] = v * d2 + (OUT_BIAS ? bout[n] : 0.f);
            }
        }
    }
}

// ---------------- CSR gather: 16 lanes per node, us8 (16B) per lane, 16 nodes/block ------
// out[d] = init(out[d]) + sum_e bf16(h[src_e]) * norm_e
__global__ __launch_bounds__(256) void k_gather(const ushort* __restrict__ h,
                                                const int* __restrict__ rowptr,
                                                const uint* __restrict__ csr,
                                                float* __restrict__ out) {
    const int tid = threadIdx.x;
    const int node = blockIdx.x * 16 + (tid >> 4);
    if (node >= NN) return;
    const int lane = tid & 15;
    const int c = lane * 8;
    const int beg = rowptr[node];
    const int end = rowptr[node + 1];

    float* op = out + (size_t)node * C_HID + c;
    float4 a0 = *(const float4*)(op);      // self-loop init
    float4 a1 = *(const float4*)(op + 4);

    for (int j0 = beg; j0 < end; j0 += 16) {
        const int n = end - j0;
        uint myE = 0;
        if (lane < n) myE = csr[j0 + lane];
        const int m = n < 16 ? n : 16;
        int jj = 0;
        for (; jj + 4 <= m; jj += 4) {
            const uint e0 = (uint)__shfl((int)myE, jj + 0, 16);
            const uint e1 = (uint)__shfl((int)myE, jj + 1, 16);
            const uint e2 = (uint)__shfl((int)myE, jj + 2, 16);
            const uint e3 = (uint)__shfl((int)myE, jj + 3, 16);
            const us8 u0 = *(const us8*)(h + (size_t)(e0 >> 16) * C_HID + c);
            const us8 u1 = *(const us8*)(h + (size_t)(e1 >> 16) * C_HID + c);
            const us8 u2 = *(const us8*)(h + (size_t)(e2 >> 16) * C_HID + c);
            const us8 u3 = *(const us8*)(h + (size_t)(e3 >> 16) * C_HID + c);
            const float n0 = __half2float(__ushort_as_half((ushort)(e0 & 0xffffu)));
            const float n1 = __half2float(__ushort_as_half((ushort)(e1 & 0xffffu)));
            const float n2 = __half2float(__ushort_as_half((ushort)(e2 & 0xffffu)));
            const float n3 = __half2float(__ushort_as_half((ushort)(e3 & 0xffffu)));
            a0.x = fmaf(bf2f(u0[0]), n0, a0.x);
            a0.y = fmaf(bf2f(u0[1]), n0, a0.y);
            a0.z = fmaf(bf2f(u0[2]), n0, a0.z);
            a0.w = fmaf(bf2f(u0[3]), n0, a0.w);
            a1.x = fmaf(bf2f(u0[4]), n0, a1.x);
            a1.y = fmaf(bf2f(u0[5]), n0, a1.y);
            a1.z = fmaf(bf2f(u0[6]), n0, a1.z);
            a1.w = fmaf(bf2f(u0[7]), n0, a1.w);
            a0.x = fmaf(bf2f(u1[0]), n1, a0.x);
            a0.y = fmaf(bf2f(u1[1]), n1, a0.y);
            a0.z = fmaf(bf2f(u1[2]), n1, a0.z);
            a0.w = fmaf(bf2f(u1[3]), n1, a0.w);
            a1.x = fmaf(bf2f(u1[4]), n1, a1.x);
            a1.y = fmaf(bf2f(u1[5]), n1, a1.y);
            a1.z = fmaf(bf2f(u1[6]), n1, a1.z);
            a1.w = fmaf(bf2f(u1[7]), n1, a1.w);
            a0.x = fmaf(bf2f(u2[0]), n2, a0.x);
            a0.y = fmaf(bf2f(u2[1]), n2, a0.y);
            a0.z = fmaf(bf2f(u2[2]), n2, a0.z);
            a0.w = fmaf(bf2f(u2[3]), n2, a0.w);
            a1.x = fmaf(bf2f(u2[4]), n2, a1.x);
            a1.y = fmaf(bf2f(u2[5]), n2, a1.y);
            a1.z = fmaf(bf2f(u2[6]), n2, a1.z);
            a1.w = fmaf(bf2f(u2[7]), n2, a1.w);
            a0.x = fmaf(bf2f(u3[0]), n3, a0.x);
            a0.y = fmaf(bf2f(u3[1]), n3, a0.y);
            a0.z = fmaf(bf2f(u3[2]), n3, a0.z);
            a0.w = fmaf(bf2f(u3[3]), n3, a0.w);
            a1.x = fmaf(bf2f(u3[4]), n3, a1.x);
            a1.y = fmaf(bf2f(u3[5]), n3, a1.y);
            a1.z = fmaf(bf2f(u3[6]), n3, a1.z);
            a1.w = fmaf(bf2f(u3[7]), n3, a1.w);
        }
        for (; jj < m; ++jj) {
            const uint ev = (uint)__shfl((int)myE, jj, 16);
            const us8 u = *(const us8*)(h + (size_t)(ev >> 16) * C_HID + c);
            const float nw = __half2float(__ushort_as_half((ushort)(ev & 0xffffu)));
            a0.x = fmaf(bf2f(u[0]), nw, a0.x);
            a0.y = fmaf(bf2f(u[1]), nw, a0.y);
            a0.z = fmaf(bf2f(u[2]), nw, a0.z);
            a0.w = fmaf(bf2f(u[3]), nw, a0.w);
            a1.x = fmaf(bf2f(u[4]), nw, a1.x);
            a1.y = fmaf(bf2f(u[5]), nw, a1.y);
            a1.z = fmaf(bf2f(u[6]), nw, a1.z);
            a1.w = fmaf(bf2f(u[7]), nw, a1.w);
        }
    }
    *(float4*)(op) = a0;
    *(float4*)(op + 4) = a1;
}

extern "C" void kernel_launch(void* const* d_in, const int* in_sizes, int n_in,
                              void* d_out, int out_size, void* d_ws, size_t ws_size,
                              hipStream_t stream) {
    const float* x = (const float*)d_in[0];
    const int* ei = (const int*)d_in[1];
    const float* W1 = (const float*)d_in[2];
    const float* b1 = (const float*)d_in[3];
    const float* W2 = (const float*)d_in[4];
    const float* b2 = (const float*)d_in[5];
    float* out = (float*)d_out;

    const int* src = ei;
    const int* dst = ei + NE;

    // workspace layout (4-byte units)
    int* cnt = (int*)d_ws;                       // 50048 (unused)
    int* rowptr = cnt + 50048;                   // 50064 (NN+1)
    float* dinv = (float*)(rowptr + 50064);      // 50048
    int* bsum = (int*)(dinv + 50048);            // 256 (unused)
    int* bpre = bsum + 256;                      // 256 (unused)
    int* histT = bpre + 256;                     // 16384
    int* histS = histT + 16384;                  // 16384
    ushort* Wt1 = (ushort*)(histS + 16384);      // 98304 shorts (frag-linear hi+lo)
    ushort* Wt2 = Wt1 + 98304;                   // 32768 shorts
    uint* csr = (uint*)(Wt2 + 32768);            // NE uints
    uint2* mid = (uint2*)(csr + NE);             // NE uint2
    ushort* A_bf = (ushort*)(mid + NE);          // NN*128 shorts (h bf16)
    float* B = (float*)(A_bf + (size_t)NN * C_HID);  // NN*128 fp32 (agg buffer)

    k_wconv2<<<(C_IN * C_HID + C_HID * C_HID + 255) / 256, 256, 0, stream>>>(W1, W2, Wt1, Wt2);
    k_hist<<<CHK, 256, 0, stream>>>(dst, histT);
    k_hscan<<<1, 1024, 0, stream>>>(histT, histS);
    k_binscat<<<CHK, 256, 0, stream>>>(src, dst, histS, mid);
    k_bcnt_scan<<<NBKT, 256, 0, stream>>>(mid, histS, rowptr, dinv);
    k_binfill<<<NBKT, 256, 0, stream>>>(mid, histS, rowptr, dinv, csr);

    const int gblocks = (NN + 63) / 64;
    const int agblocks = (NN + 15) / 16;
    // layer 1: h1 = x@W1 -> A_bf (bf16) ;  B = h1*dinv^2 (fp32 self-loop init)
    k_gemm_mfma<false, false><<<gblocks, 512, 0, stream>>>(x, Wt1, nullptr, nullptr, dinv, A_bf, B, C_IN);
    // B += gather(h1)
    k_gather<<<agblocks, 256, 0, stream>>>(A_bf, rowptr, csr, B);
    // layer 2: h2 = relu(B + b1)@W2 -> A_bf ; out = h2*dinv^2 + b2 (self-loop init)
    k_gemm_mfma<true, true><<<gblocks, 512, 0, stream>>>(B, Wt2, b1, b2, dinv, A_bf, out, C_HID);
    // out += gather(h2)
    k_gather<<<agblocks, 256, 0, stream>>>(A_bf, rowptr, csr, out);
}

// Round 10
// 290.146 us; speedup vs baseline: 1.2224x; 1.0233x over previous
//
#include <hip/hip_runtime.h>
#include <hip/hip_fp16.h>

#define NN 50000
#define NE 800000
#define C_IN 384
#define C_HID 128
#define CHK 128   // edge chunks
#define ECH 6250  // edges per chunk (128*6250 = 800000)
#define NBKT 128  // dst buckets
#define BSTR 392  // dst stride per bucket (128*392 = 50176 >= NN)
#define GBLK 782  // gemm blocks for BM=64 (ceil(50000/64))

typedef __attribute__((ext_vector_type(8))) short short8;
typedef __attribute__((ext_vector_type(4))) float f32x4;
typedef __attribute__((ext_vector_type(8))) unsigned short us8;

__device__ __forceinline__ ushort f2bf(float x) {
    uint u = __float_as_uint(x);
    uint r = (u + 0x7fffu + ((u >> 16) & 1u)) >> 16;  // RNE
    return (ushort)r;
}
__device__ __forceinline__ float bf2f(ushort b) { return __uint_as_float(((uint)b) << 16); }

typedef __attribute__((address_space(1))) const unsigned int as1_uint;
typedef __attribute__((address_space(3))) unsigned int as3_uint;
__device__ __forceinline__ void gload16(const void* g, void* l) {
    __builtin_amdgcn_global_load_lds((as1_uint*)g, (as3_uint*)l, 16, 0, 0);
}

// ---------------- W frag-linear hi/lo split helper ----------------
__device__ __forceinline__ void wconv_one(const float* W, ushort* Wt, int i) {
    int k = i >> 7, n = i & 127;  // N = 128
    float w = W[i];
    ushort h = f2bf(w);
    ushort l = f2bf(w - bf2f(h));
    int blk = k >> 5, kq = (k >> 3) & 3, j = k & 7;
    int t = n >> 4, fr = n & 15, lane = kq * 16 + fr;
    size_t off = ((size_t)blk * 1024 + t * 64 + lane) * 8 + j;
    Wt[off] = h;
    Wt[off + 4096] = l;  // +512 short8
}

// ---------------- k_prep: hist (blocks 0..127, chunk-major histT) U wconv ----------------
__global__ __launch_bounds__(256) void k_prep(const int* __restrict__ dst,
                                              int* __restrict__ histT,
                                              const float* __restrict__ W1,
                                              const float* __restrict__ W2,
                                              ushort* __restrict__ Wt1,
                                              ushort* __restrict__ Wt2) {
    const int tid = threadIdx.x;
    if (blockIdx.x < CHK) {
        __shared__ int h[NBKT];
        if (tid < NBKT) h[tid] = 0;
        __syncthreads();
        const int base = blockIdx.x * ECH;
        for (int i = base + tid; i < base + ECH; i += 256)
            atomicAdd(&h[(uint)dst[i] / BSTR], 1);
        __syncthreads();
        if (tid < NBKT) histT[blockIdx.x * NBKT + tid] = h[tid];  // chunk-major
    } else {
        int i = (blockIdx.x - CHK) * 256 + tid;
        if (i < C_IN * C_HID) {
            wconv_one(W1, Wt1, i);
        } else {
            int j = i - C_IN * C_HID;
            if (j < C_HID * C_HID) wconv_one(W2, Wt2, j);
        }
    }
}

// ---------------- k_binscat: self-computed offsets (replaces histS round-trip) ------------
// cur[k] = global_bucket_base[k] + sum_{c' < myc} histT[c'][k]  (== R9's histS[k*CHK+myc])
__global__ __launch_bounds__(256) void k_binscat(const int* __restrict__ src,
                                                 const int* __restrict__ dst,
                                                 const int* __restrict__ histT,
                                                 uint2* __restrict__ mid) {
    __shared__ int cur[NBKT];
    __shared__ int sc[NBKT];
    const int tid = threadIdx.x;
    const int myc = blockIdx.x;
    int tot = 0;
    if (tid < NBKT) {
        int part = 0;
        for (int c = 0; c < CHK; ++c) {
            int v = histT[c * NBKT + tid];
            tot += v;
            if (c < myc) part += v;
        }
        sc[tid] = tot;
        cur[tid] = part;
    }
    __syncthreads();
    for (int off = 1; off < NBKT; off <<= 1) {
        int v = 0;
        if (tid < NBKT && tid >= off) v = sc[tid - off];
        __syncthreads();
        if (tid < NBKT) sc[tid] += v;
        __syncthreads();
    }
    if (tid < NBKT) cur[tid] += sc[tid] - tot;  // + exclusive bucket base
    __syncthreads();
    const int base = myc * ECH;
    for (int i = base + tid; i < base + ECH; i += 256) {
        const int s = src[i];
        const int d = dst[i];
        const int p = atomicAdd(&cur[(uint)d / BSTR], 1);
        mid[p] = make_uint2((uint)d, (uint)s << 16);
    }
}

// ---------------- k_bcnt_scan: counts + within-bucket scan -> rowptr + dinv ----------------
// lo/hi self-computed from histT column sums (== R9's histS[b*CHK] semantics).
// Scan writes guarded by i0 < BSTR (R8 cross-bucket race fix).
__global__ __launch_bounds__(256) void k_bcnt_scan(const uint2* __restrict__ mid,
                                                   const int* __restrict__ histT,
                                                   int* __restrict__ rowptr,
                                                   float* __restrict__ dinv) {
    __shared__ int cur[BSTR];
    __shared__ int part[256];
    __shared__ int sc[NBKT];
    __shared__ int sLO, sHI;
    const int tid = threadIdx.x;
    const int b = blockIdx.x;
    for (int j = tid; j < BSTR; j += 256) cur[j] = 0;
    int tot = 0;
    if (tid < NBKT) {
        for (int c = 0; c < CHK; ++c) tot += histT[c * NBKT + tid];
        sc[tid] = tot;
    }
    __syncthreads();
    for (int off = 1; off < NBKT; off <<= 1) {
        int v = 0;
        if (tid < NBKT && tid >= off) v = sc[tid - off];
        __syncthreads();
        if (tid < NBKT) sc[tid] += v;
        __syncthreads();
    }
    if (tid == b) { sLO = sc[b] - tot; sHI = sc[b]; }  // tot == tot[b] on thread b
    __syncthreads();
    const int lo = sLO, hi = sHI;
    for (int e = lo + tid; e < hi; e += 256)
        atomicAdd(&cur[mid[e].x - (uint)b * BSTR], 1);
    __syncthreads();
    const int i0 = 2 * tid;
    const int v0 = (i0 < BSTR) ? cur[i0] : 0;
    const int v1 = (i0 + 1 < BSTR) ? cur[i0 + 1] : 0;
    part[tid] = v0 + v1;
    __syncthreads();
    for (int off = 1; off < 256; off <<= 1) {
        int v = (tid >= off) ? part[tid - off] : 0;
        __syncthreads();
        part[tid] += v;
        __syncthreads();
    }
    const int base = lo + ((tid > 0) ? part[tid - 1] : 0);
    const int idx0 = b * BSTR + i0;
    if (i0 < BSTR && idx0 < NN) {
        rowptr[idx0] = base;
        dinv[idx0] = rsqrtf((float)v0 + 1.0f);  // +1 = self loop
    }
    if (i0 + 1 < BSTR && idx0 + 1 < NN) {
        rowptr[idx0 + 1] = base + v0;
        dinv[idx0 + 1] = rsqrtf((float)v1 + 1.0f);
    }
    if (b == NBKT - 1 && tid == 0) rowptr[NN] = NE;
}

// ---------------- split-bf16 MFMA GEMM, BM=64, 8 waves, K_STEP=32  (+fused binfill) --------
#define STAGE_X(NXT, XOLD, KB1)                                                          \
    {                                                                                    \
        float xs0 = XOLD.x, xs1 = XOLD.y, xs2 = XOLD.z, xs3 = XOLD.w;                    \
        if (IN_RELU_BIAS) {                                                              \
            float4 bq = *(const float4*)(&bias_lds[(KB1) * 32 + (tid & 7) * 4]);         \
            xs0 = fmaxf(xs0 + bq.x, 0.f);                                                \
            xs1 = fmaxf(xs1 + bq.y, 0.f);                                                \
            xs2 = fmaxf(xs2 + bq.z, 0.f);                                                \
            xs3 = fmaxf(xs3 + bq.w, 0.f);                                                \
        }                                                                                \
        const uint u0 = __float_as_uint(xs0), u1 = __float_as_uint(xs1);                 \
        const uint u2 = __float_as_uint(xs2), u3 = __float_as_uint(xs3);                 \
        const uint h01 = (u0 >> 16) | (u1 & 0xffff0000u);                                \
        const uint h23 = (u2 >> 16) | (u3 & 0xffff0000u);                                \
        const uint l0 = __float_as_uint(xs0 - __uint_as_float(u0 & 0xffff0000u));        \
        const uint l1 = __float_as_uint(xs1 - __uint_as_float(u1 & 0xffff0000u));        \
        const uint l2 = __float_as_uint(xs2 - __uint_as_float(u2 & 0xffff0000u));        \
        const uint l3 = __float_as_uint(xs3 - __uint_as_float(u3 & 0xffff0000u));        \
        const uint l01 = (l0 >> 16) | (l1 & 0xffff0000u);                                \
        const uint l23 = (l2 >> 16) | (l3 & 0xffff0000u);                                \
        *(uint2*)&XLh[NXT][xw] = make_uint2(h01, h23);                                   \
        *(uint2*)&XLl[NXT][xw] = make_uint2(l01, l23);                                   \
    }

#define GEMM_BODY(KB, CUR, NXT, XOLD, XNEW)                                              \
    {                                                                                    \
        _Pragma("unroll")                                                                \
        for (int i_ = 0; i_ < 2; ++i_)                                                   \
            gload16(Wt8 + (size_t)((KB) + 1) * 1024 + wv * 128 + i_ * 64 + lane,         \
                    &WL[NXT][wv * 128 + i_ * 64]);                                       \
        __builtin_amdgcn_sched_barrier(0);                                               \
        XNEW = *(const float4*)(xsrc + ((KB) + 2) * 32);                                 \
        const short8 ahh = *(const short8*)&XLh[CUR][axh];                               \
        const short8 all = *(const short8*)&XLl[CUR][axh];                               \
        const short8 wh0 = WL[CUR][(tb + 0) * 64 + lane];                                \
        const short8 wl0 = WL[CUR][512 + (tb + 0) * 64 + lane];                          \
        const short8 wh1 = WL[CUR][(tb + 1) * 64 + lane];                                \
        const short8 wl1 = WL[CUR][512 + (tb + 1) * 64 + lane];                          \
        const short8 wh2 = WL[CUR][(tb + 2) * 64 + lane];                                \
        const short8 wl2 = WL[CUR][512 + (tb + 2) * 64 + lane];                          \
        const short8 wh3 = WL[CUR][(tb + 3) * 64 + lane];                                \
        const short8 wl3 = WL[CUR][512 + (tb + 3) * 64 + lane];                          \
        STAGE_X(NXT, XOLD, (KB) + 1);                                                    \
        __builtin_amdgcn_s_setprio(1);                                                   \
        acc[0] = __builtin_amdgcn_mfma_f32_16x16x32_bf16(ahh, wh0, acc[0], 0, 0, 0);     \
        acc[0] = __builtin_amdgcn_mfma_f32_16x16x32_bf16(ahh, wl0, acc[0], 0, 0, 0);     \
        acc[0] = __builtin_amdgcn_mfma_f32_16x16x32_bf16(all, wh0, acc[0], 0, 0, 0);     \
        acc[1] = __builtin_amdgcn_mfma_f32_16x16x32_bf16(ahh, wh1, acc[1], 0, 0, 0);     \
        acc[1] = __builtin_amdgcn_mfma_f32_16x16x32_bf16(ahh, wl1, acc[1], 0, 0, 0);     \
        acc[1] = __builtin_amdgcn_mfma_f32_16x16x32_bf16(all, wh1, acc[1], 0, 0, 0);     \
        acc[2] = __builtin_amdgcn_mfma_f32_16x16x32_bf16(ahh, wh2, acc[2], 0, 0, 0);     \
        acc[2] = __builtin_amdgcn_mfma_f32_16x16x32_bf16(ahh, wl2, acc[2], 0, 0, 0);     \
        acc[2] = __builtin_amdgcn_mfma_f32_16x16x32_bf16(all, wh2, acc[2], 0, 0, 0);     \
        acc[3] = __builtin_amdgcn_mfma_f32_16x16x32_bf16(ahh, wh3, acc[3], 0, 0, 0);     \
        acc[3] = __builtin_amdgcn_mfma_f32_16x16x32_bf16(ahh, wl3, acc[3], 0, 0, 0);     \
        acc[3] = __builtin_amdgcn_mfma_f32_16x16x32_bf16(all, wh3, acc[3], 0, 0, 0);     \
        __builtin_amdgcn_s_setprio(0);                                                   \
        __builtin_amdgcn_sched_barrier(0);                                               \
        asm volatile("s_waitcnt vmcnt(1) lgkmcnt(0)" ::: "memory");                      \
        __builtin_amdgcn_sched_barrier(0);                                               \
        __builtin_amdgcn_s_barrier();                                                    \
    }

#define GEMM_TAIL(CUR)                                                                   \
    {                                                                                    \
        const short8 ahh = *(const short8*)&XLh[CUR][axh];                               \
        const short8 all = *(const short8*)&XLl[CUR][axh];                               \
        const short8 wh0 = WL[CUR][(tb + 0) * 64 + lane];                                \
        const short8 wl0 = WL[CUR][512 + (tb + 0) * 64 + lane];                          \
        const short8 wh1 = WL[CUR][(tb + 1) * 64 + lane];                                \
        const short8 wl1 = WL[CUR][512 + (tb + 1) * 64 + lane];                          \
        const short8 wh2 = WL[CUR][(tb + 2) * 64 + lane];                                \
        const short8 wl2 = WL[CUR][512 + (tb + 2) * 64 + lane];                          \
        const short8 wh3 = WL[CUR][(tb + 3) * 64 + lane];                                \
        const short8 wl3 = WL[CUR][512 + (tb + 3) * 64 + lane];                          \
        acc[0] = __builtin_amdgcn_mfma_f32_16x16x32_bf16(ahh, wh0, acc[0], 0, 0, 0);     \
        acc[0] = __builtin_amdgcn_mfma_f32_16x16x32_bf16(ahh, wl0, acc[0], 0, 0, 0);     \
        acc[0] = __builtin_amdgcn_mfma_f32_16x16x32_bf16(all, wh0, acc[0], 0, 0, 0);     \
        acc[1] = __builtin_amdgcn_mfma_f32_16x16x32_bf16(ahh, wh1, acc[1], 0, 0, 0);     \
        acc[1] = __builtin_amdgcn_mfma_f32_16x16x32_bf16(ahh, wl1, acc[1], 0, 0, 0);     \
        acc[1] = __builtin_amdgcn_mfma_f32_16x16x32_bf16(all, wh1, acc[1], 0, 0, 0);     \
        acc[2] = __builtin_amdgcn_mfma_f32_16x16x32_bf16(ahh, wh2, acc[2], 0, 0, 0);     \
        acc[2] = __builtin_amdgcn_mfma_f32_16x16x32_bf16(ahh, wl2, acc[2], 0, 0, 0);     \
        acc[2] = __builtin_amdgcn_mfma_f32_16x16x32_bf16(all, wh2, acc[2], 0, 0, 0);     \
        acc[3] = __builtin_amdgcn_mfma_f32_16x16x32_bf16(ahh, wh3, acc[3], 0, 0, 0);     \
        acc[3] = __builtin_amdgcn_mfma_f32_16x16x32_bf16(ahh, wl3, acc[3], 0, 0, 0);     \
        acc[3] = __builtin_amdgcn_mfma_f32_16x16x32_bf16(all, wh3, acc[3], 0, 0, 0);     \
    }

template <bool IN_RELU_BIAS, bool OUT_BIAS, bool FILL>
__global__ __launch_bounds__(512) void k_gemm_mfma(const float* __restrict__ X,
                                                   const ushort* __restrict__ Wt,
                                                   const float* __restrict__ bin,
                                                   const float* __restrict__ bout,
                                                   const float* __restrict__ dinv,
                                                   ushort* __restrict__ out_main,
                                                   float* __restrict__ out_self,
                                                   int K,
                                                   const uint2* __restrict__ mid,
                                                   const int* __restrict__ histT,
                                                   const int* __restrict__ rowptr,
                                                   uint* __restrict__ csr) {
    __shared__ short8 WL[2][1024];    // 2 x 16 KB W double buffer (frag-linear hi+lo)
    __shared__ ushort XLh[2][2048];   // 2 x 4 KB X hi (64 rows x 32 k, swizzled)
    __shared__ ushort XLl[2][2048];   // 2 x 4 KB X lo
    __shared__ float bias_lds[128];
    __shared__ int sLO, sHI;          // fill path

    const int tid = threadIdx.x;

    if (FILL && blockIdx.x >= GBLK) {
        // ---- fused binfill: one block per bucket, 512 threads; LDS aliased into WL ----
        const int b = blockIdx.x - GBLK;
        int* cur = (int*)&WL[0][0];          // 392 ints   (0..1568 B)
        float* sdv = (float*)&WL[0][256];    // 392 floats (4096..5664 B)
        int* sc = (int*)&WL[1][0];           // 128 ints   (16 KB offset)
        int tot = 0;
        if (tid < NBKT) {
            for (int c = 0; c < CHK; ++c) tot += histT[c * NBKT + tid];
            sc[tid] = tot;
        }
        __syncthreads();
        for (int off = 1; off < NBKT; off <<= 1) {
            int v = 0;
            if (tid < NBKT && tid >= off) v = sc[tid - off];
            __syncthreads();
            if (tid < NBKT) sc[tid] += v;
            __syncthreads();
        }
        if (tid == b) { sLO = sc[b] - tot; sHI = sc[b]; }
        __syncthreads();
        const int lo = sLO, hi = sHI;
        for (int j = tid; j < BSTR; j += 512) {
            const int idx = b * BSTR + j;
            cur[j] = (idx < NN) ? rowptr[idx] : 0;
            sdv[j] = (idx < NN) ? dinv[idx] : 0.f;
        }
        __syncthreads();
        for (int e = lo + tid; e < hi; e += 512) {
            const uint2 u = mid[e];
            const int j = u.x - (uint)b * BSTR;
            const float norm = dinv[u.y >> 16] * sdv[j];
            const int p = atomicAdd(&cur[j], 1);
            csr[p] = u.y | __half_as_ushort(__float2half(norm));
        }
        return;
    }

    const int bm = blockIdx.x * 64;
    const int wv = tid >> 6;
    const int lane = tid & 63;
    const int fr = lane & 15;
    const int kq = lane >> 4;
    const int g = wv >> 1;   // 0..3 row-group
    const int ch = wv & 1;   // col half
    const int tb = ch * 4;   // first col tile
    const int NK = K >> 5;   // 12 (K=384) or 4 (K=128)

    const short8* Wt8 = (const short8*)Wt;

    const int xr = tid >> 3;   // 0..63 row in tile
    const int xc8 = tid & 7;   // 8B half-chunk index
    int xrow = bm + xr;
    if (xrow >= NN) xrow = NN - 1;
    const float* xsrc = X + (size_t)xrow * K + xc8 * 4;
    const int xw = xr * 32 + (((xc8 >> 1) ^ (xr & 3)) << 3) + ((xc8 & 1) << 2);

    const int ar = g * 16 + fr;
    const int axh = ar * 32 + ((kq ^ (ar & 3)) << 3);

    f32x4 acc[4];
#pragma unroll
    for (int t = 0; t < 4; ++t) acc[t] = (f32x4){0.f, 0.f, 0.f, 0.f};

    if (IN_RELU_BIAS && tid < 128) bias_lds[tid] = bin[tid];

    // ---- prologue ----
#pragma unroll
    for (int i_ = 0; i_ < 2; ++i_)
        gload16(Wt8 + (size_t)wv * 128 + i_ * 64 + lane, &WL[0][wv * 128 + i_ * 64]);
    __builtin_amdgcn_sched_barrier(0);
    float4 xA = *(const float4*)(xsrc);        // X(0)
    float4 xB = *(const float4*)(xsrc + 32);   // X(1)
    asm volatile("s_waitcnt lgkmcnt(0)" ::: "memory");
    __builtin_amdgcn_s_barrier();
    STAGE_X(0, xA, 0);
    xA = xB;
    asm volatile("s_waitcnt lgkmcnt(0)" ::: "memory");
    __builtin_amdgcn_s_barrier();

    for (int kb = 0; kb < NK - 2; kb += 2) {
        GEMM_BODY(kb, 0, 1, xA, xB);
        GEMM_BODY(kb + 1, 1, 0, xB, xA);
    }

    {
        const int KB = NK - 2;
#pragma unroll
        for (int i_ = 0; i_ < 2; ++i_)
            gload16(Wt8 + (size_t)(KB + 1) * 1024 + wv * 128 + i_ * 64 + lane,
                    &WL[1][wv * 128 + i_ * 64]);
        STAGE_X(1, xA, KB + 1);
        GEMM_TAIL(0);
        __builtin_amdgcn_sched_barrier(0);
        asm volatile("s_waitcnt vmcnt(0) lgkmcnt(0)" ::: "memory");
        __builtin_amdgcn_sched_barrier(0);
        __builtin_amdgcn_s_barrier();
    }
    GEMM_TAIL(1);

#pragma unroll
    for (int r = 0; r < 4; ++r) {
        const int m = bm + g * 16 + kq * 4 + r;
        if (m < NN) {
            const float dv = dinv[m];
            const float d2 = dv * dv;
            ushort* om = out_main + (size_t)m * C_HID;
            float* os = out_self + (size_t)m * C_HID;
#pragma unroll
            for (int t = 0; t < 4; ++t) {
                const int n = (ch * 4 + t) * 16 + fr;
                const float v = acc[t][r];
                om[n] = f2bf(v);
                os[n] = v * d2 + (OUT_BIAS ? bout[n] : 0.f);
            }
        }
    }
}

// ---------------- CSR gather: 16 lanes per node, us8 (16B) per lane, 16 nodes/block ------
__global__ __launch_bounds__(256) void k_gather(const ushort* __restrict__ h,
                                                const int* __restrict__ rowptr,
                                                const uint* __restrict__ csr,
                                                float* __restrict__ out) {
    const int tid = threadIdx.x;
    const int node = blockIdx.x * 16 + (tid >> 4);
    if (node >= NN) return;
    const int lane = tid & 15;
    const int c = lane * 8;
    const int beg = rowptr[node];
    const int end = rowptr[node + 1];

    float* op = out + (size_t)node * C_HID + c;
    float4 a0 = *(const float4*)(op);      // self-loop init
    float4 a1 = *(const float4*)(op + 4);

    for (int j0 = beg; j0 < end; j0 += 16) {
        const int n = end - j0;
        uint myE = 0;
        if (lane < n) myE = csr[j0 + lane];
        const int m = n < 16 ? n : 16;
        int jj = 0;
        for (; jj + 4 <= m; jj += 4) {
            const uint e0 = (uint)__shfl((int)myE, jj + 0, 16);
            const uint e1 = (uint)__shfl((int)myE, jj + 1, 16);
            const uint e2 = (uint)__shfl((int)myE, jj + 2, 16);
            const uint e3 = (uint)__shfl((int)myE, jj + 3, 16);
            const us8 u0 = *(const us8*)(h + (size_t)(e0 >> 16) * C_HID + c);
            const us8 u1 = *(const us8*)(h + (size_t)(e1 >> 16) * C_HID + c);
            const us8 u2 = *(const us8*)(h + (size_t)(e2 >> 16) * C_HID + c);
            const us8 u3 = *(const us8*)(h + (size_t)(e3 >> 16) * C_HID + c);
            const float n0 = __half2float(__ushort_as_half((ushort)(e0 & 0xffffu)));
            const float n1 = __half2float(__ushort_as_half((ushort)(e1 & 0xffffu)));
            const float n2 = __half2float(__ushort_as_half((ushort)(e2 & 0xffffu)));
            const float n3 = __half2float(__ushort_as_half((ushort)(e3 & 0xffffu)));
            a0.x = fmaf(bf2f(u0[0]), n0, a0.x);
            a0.y = fmaf(bf2f(u0[1]), n0, a0.y);
            a0.z = fmaf(bf2f(u0[2]), n0, a0.z);
            a0.w = fmaf(bf2f(u0[3]), n0, a0.w);
            a1.x = fmaf(bf2f(u0[4]), n0, a1.x);
            a1.y = fmaf(bf2f(u0[5]), n0, a1.y);
            a1.z = fmaf(bf2f(u0[6]), n0, a1.z);
            a1.w = fmaf(bf2f(u0[7]), n0, a1.w);
            a0.x = fmaf(bf2f(u1[0]), n1, a0.x);
            a0.y = fmaf(bf2f(u1[1]), n1, a0.y);
            a0.z = fmaf(bf2f(u1[2]), n1, a0.z);
            a0.w = fmaf(bf2f(u1[3]), n1, a0.w);
            a1.x = fmaf(bf2f(u1[4]), n1, a1.x);
            a1.y = fmaf(bf2f(u1[5]), n1, a1.y);
            a1.z = fmaf(bf2f(u1[6]), n1, a1.z);
            a1.w = fmaf(bf2f(u1[7]), n1, a1.w);
            a0.x = fmaf(bf2f(u2[0]), n2, a0.x);
            a0.y = fmaf(bf2f(u2[1]), n2, a0.y);
            a0.z = fmaf(bf2f(u2[2]), n2, a0.z);
            a0.w = fmaf(bf2f(u2[3]), n2, a0.w);
            a1.x = fmaf(bf2f(u2[4]), n2, a1.x);
            a1.y = fmaf(bf2f(u2[5]), n2, a1.y);
            a1.z = fmaf(bf2f(u2[6]), n2, a1.z);
            a1.w = fmaf(bf2f(u2[7]), n2, a1.w);
            a0.x = fmaf(bf2f(u3[0]), n3, a0.x);
            a0.y = fmaf(bf2f(u3[1]), n3, a0.y);
            a0.z = fmaf(bf2f(u3[2]), n3, a0.z);
            a0.w = fmaf(bf2f(u3[3]), n3, a0.w);
            a1.x = fmaf(bf2f(u3[4]), n3, a1.x);
            a1.y = fmaf(bf2f(u3[5]), n3, a1.y);
            a1.z = fmaf(bf2f(u3[6]), n3, a1.z);
            a1.w = fmaf(bf2f(u3[7]), n3, a1.w);
        }
        for (; jj < m; ++jj) {
            const uint ev = (uint)__shfl((int)myE, jj, 16);
            const us8 u = *(const us8*)(h + (size_t)(ev >> 16) * C_HID + c);
            const float nw = __half2float(__ushort_as_half((ushort)(ev & 0xffffu)));
            a0.x = fmaf(bf2f(u[0]), nw, a0.x);
            a0.y = fmaf(bf2f(u[1]), nw, a0.y);
            a0.z = fmaf(bf2f(u[2]), nw, a0.z);
            a0.w = fmaf(bf2f(u[3]), nw, a0.w);
            a1.x = fmaf(bf2f(u[4]), nw, a1.x);
            a1.y = fmaf(bf2f(u[5]), nw, a1.y);
            a1.z = fmaf(bf2f(u[6]), nw, a1.z);
            a1.w = fmaf(bf2f(u[7]), nw, a1.w);
        }
    }
    *(float4*)(op) = a0;
    *(float4*)(op + 4) = a1;
}

extern "C" void kernel_launch(void* const* d_in, const int* in_sizes, int n_in,
                              void* d_out, int out_size, void* d_ws, size_t ws_size,
                              hipStream_t stream) {
    const float* x = (const float*)d_in[0];
    const int* ei = (const int*)d_in[1];
    const float* W1 = (const float*)d_in[2];
    const float* b1 = (const float*)d_in[3];
    const float* W2 = (const float*)d_in[4];
    const float* b2 = (const float*)d_in[5];
    float* out = (float*)d_out;

    const int* src = ei;
    const int* dst = ei + NE;

    // workspace layout (4-byte units)
    int* cnt = (int*)d_ws;                       // 50048 (unused)
    int* rowptr = cnt + 50048;                   // 50064 (NN+1)
    float* dinv = (float*)(rowptr + 50064);      // 50048
    int* bsum = (int*)(dinv + 50048);            // 256 (unused)
    int* bpre = bsum + 256;                      // 256 (unused)
    int* histT = bpre + 256;                     // 16384 (chunk-major)
    int* histS = histT + 16384;                  // 16384 (unused now)
    ushort* Wt1 = (ushort*)(histS + 16384);      // 98304 shorts (frag-linear hi+lo)
    ushort* Wt2 = Wt1 + 98304;                   // 32768 shorts
    uint* csr = (uint*)(Wt2 + 32768);            // NE uints
    uint2* mid = (uint2*)(csr + NE);             // NE uint2
    ushort* A_bf = (ushort*)(mid + NE);          // NN*128 shorts (h bf16)
    float* B = (float*)(A_bf + (size_t)NN * C_HID);  // NN*128 fp32 (agg buffer)

    const int wblocks = (C_IN * C_HID + C_HID * C_HID + 255) / 256;  // 256
    const int agblocks = (NN + 15) / 16;

    // 1: hist U wconv
    k_prep<<<CHK + wblocks, 256, 0, stream>>>(dst, histT, W1, W2, Wt1, Wt2);
    // 2: bucket scatter (self-computed offsets)
    k_binscat<<<CHK, 256, 0, stream>>>(src, dst, histT, mid);
    // 3: counts + scan -> rowptr + dinv
    k_bcnt_scan<<<NBKT, 256, 0, stream>>>(mid, histT, rowptr, dinv);
    // 4: layer-1 GEMM U binfill (csr build hides under GEMM)
    k_gemm_mfma<false, false, true><<<GBLK + NBKT, 512, 0, stream>>>(
        x, Wt1, nullptr, nullptr, dinv, A_bf, B, C_IN, mid, histT, rowptr, csr);
    // 5: B += gather(h1)
    k_gather<<<agblocks, 256, 0, stream>>>(A_bf, rowptr, csr, B);
    // 6: layer-2 GEMM
    k_gemm_mfma<true, true, false><<<GBLK, 512, 0, stream>>>(
        B, Wt2, b1, b2, dinv, A_bf, out, C_HID, nullptr, nullptr, nullptr, nullptr);
    // 7: out += gather(h2)
    k_gather<<<agblocks, 256, 0, stream>>>(A_bf, rowptr, csr, out);
}